// Round 10
// baseline (449.141 us; speedup 1.0000x reference)
//
#include <hip/hip_runtime.h>

#define NN 100000
#define NE 1600000
#define FD 128
#define CO 10
#define BN_EPS 1e-5f
#define SCAN_B 1024
#define SCAN_NB ((NN + SCAN_B - 1) / SCAN_B)   // 98
#define NBUK ((NN + 127) / 128)                // 782 buckets of 128 nodes
#define NBUKP 784                              // padded row for histM/segbase
#define BCAP 3072
#define SEGE 4096
#define NSEG ((NE + SEGE - 1) / SEGE)          // 391

typedef __attribute__((ext_vector_type(8))) short short8;
typedef __attribute__((ext_vector_type(4))) float f32x4;

__device__ __forceinline__ unsigned short f2bf(float f) {
  unsigned int u = __builtin_bit_cast(unsigned int, f);
  u = (u + 0x7FFFu + ((u >> 16) & 1u)) >> 16;
  return (unsigned short)u;
}
__device__ __forceinline__ float bf2f(unsigned short h) {
  unsigned int u = ((unsigned int)h) << 16;
  return __builtin_bit_cast(float, u);
}
__device__ __forceinline__ float blo(unsigned int u) {
  return __builtin_bit_cast(float, u << 16);
}
__device__ __forceinline__ float bhi(unsigned int u) {
  return __builtin_bit_cast(float, u & 0xFFFF0000u);
}

// ---------------- pass 1: per-segment bucket histogram (no atomics to global) --
__global__ __launch_bounds__(256) void k_hist(const int* __restrict__ dst,
                                              int* __restrict__ histM) {
  __shared__ int hist[NBUK];
  int b = blockIdx.x, t = threadIdx.x;
  for (int i = t; i < NBUK; i += 256) hist[i] = 0;
  __syncthreads();
  int e0 = b * SEGE, e1 = min(e0 + SEGE, NE);
  for (int e = e0 + t; e < e1; e += 256) atomicAdd(&hist[dst[e] >> 7], 1);
  __syncthreads();
  for (int i = t; i < NBUK; i += 256) histM[b * NBUKP + i] = hist[i];
}

// ---------------- pass 2: per-bucket prefix over segments (coalesced) --------
__global__ __launch_bounds__(256) void k_colscan(const int* __restrict__ histM,
                                                 int* __restrict__ segbase,
                                                 int* __restrict__ btot) {
  int b = blockIdx.x * 256 + threadIdx.x;
  if (b >= NBUK) return;
  int run = 0;
  for (int s = 0; s < NSEG; ++s) {
    int v = histM[s * NBUKP + b];
    segbase[s * NBUKP + b] = run;
    run += v;
  }
  btot[b] = run;
}

// ---------------- pass 3: scatter into buckets, LDS cursors, packed u32 ------
// entry = (d&127)<<17 | src   (src < 2^17)
__global__ __launch_bounds__(256) void k_scatter2(const int* __restrict__ src,
                                                  const int* __restrict__ dst,
                                                  const int* __restrict__ segbase,
                                                  unsigned int* __restrict__ buck) {
  __shared__ int base[NBUK];
  int b = blockIdx.x, t = threadIdx.x;
  for (int i = t; i < NBUK; i += 256) base[i] = segbase[b * NBUKP + i];
  __syncthreads();
  int e0 = b * SEGE, e1 = min(e0 + SEGE, NE);
  for (int e = e0 + t; e < e1; e += 256) {
    int s = src[e], d = dst[e];
    int bk = d >> 7;
    int slot = atomicAdd(&base[bk], 1);
    buck[(size_t)bk * BCAP + slot] = ((unsigned int)(d & 127) << 17) | (unsigned int)s;
  }
}

// ---------------- per-bucket degree count + fused dinv ----------------
__global__ __launch_bounds__(256) void k_bdeg(const int* __restrict__ btot,
                                              const unsigned int* __restrict__ buck,
                                              int* __restrict__ deg_i,
                                              float* __restrict__ dinv) {
  __shared__ int cnt[128];
  int b = blockIdx.x, t = threadIdx.x;
  if (t < 128) cnt[t] = 0;
  __syncthreads();
  int nb = btot[b];
  const unsigned int* bp = buck + (size_t)b * BCAP;
  for (int i = t; i < nb; i += 256) atomicAdd(&cnt[bp[i] >> 17], 1);
  __syncthreads();
  int node = b * 128 + t;
  if (t < 128 && node < NN) {
    int dg = cnt[t];
    deg_i[node] = dg;
    dinv[node] = rsqrtf((float)dg + 1.0f);
  }
}

// ---------------- exclusive scan over deg_i -> row_start ----------------
__global__ __launch_bounds__(256) void k_scan_partial(const int* __restrict__ deg_i,
                                                      int* __restrict__ blocksum) {
  __shared__ int lds[256];
  int b = blockIdx.x, t = threadIdx.x;
  int base = b * SCAN_B + t * 4;
  int s = 0;
#pragma unroll
  for (int i = 0; i < 4; ++i) {
    int idx = base + i;
    s += (idx < NN) ? deg_i[idx] : 0;
  }
  lds[t] = s;
  __syncthreads();
  for (int off = 128; off > 0; off >>= 1) {
    if (t < off) lds[t] += lds[t + off];
    __syncthreads();
  }
  if (t == 0) blocksum[b] = lds[0];
}

__global__ void k_scan_block(int* __restrict__ blocksum) {
  __shared__ int lds[128];
  int t = threadIdx.x;
  int v = (t < SCAN_NB) ? blocksum[t] : 0;
  lds[t] = v;
  __syncthreads();
  for (int off = 1; off < 128; off <<= 1) {
    int add = (t >= off) ? lds[t - off] : 0;
    __syncthreads();
    lds[t] += add;
    __syncthreads();
  }
  if (t < SCAN_NB) blocksum[t] = lds[t] - v;
}

__global__ __launch_bounds__(256) void k_scan_final(const int* __restrict__ deg_i,
                                                    const int* __restrict__ blocksum,
                                                    int* __restrict__ row_start) {
  __shared__ int lds[256];
  int b = blockIdx.x, t = threadIdx.x;
  int base = b * SCAN_B + t * 4;
  int v[4];
  int s = 0;
#pragma unroll
  for (int i = 0; i < 4; ++i) {
    int idx = base + i;
    v[i] = (idx < NN) ? deg_i[idx] : 0;
    s += v[i];
  }
  lds[t] = s;
  __syncthreads();
  int mine = s;
  for (int off = 1; off < 256; off <<= 1) {
    int add = (t >= off) ? lds[t - off] : 0;
    __syncthreads();
    lds[t] += add;
    __syncthreads();
  }
  int run = lds[t] - mine + blocksum[b];
#pragma unroll
  for (int i = 0; i < 4; ++i) {
    int idx = base + i;
    if (idx < NN) {
      row_start[idx] = run;
      run += v[i];
    }
  }
  if (b == 0 && t == 0) row_start[NN] = NE;
}

// ---------------- place pass: bucket -> CSR ----------------
__global__ __launch_bounds__(256) void k_place(const int* __restrict__ btot,
                                               const unsigned int* __restrict__ buck,
                                               const int* __restrict__ row_start,
                                               int* __restrict__ csr_src) {
  __shared__ int cnt[128];
  int b = blockIdx.x, t = threadIdx.x;
  if (t < 128) cnt[t] = 0;
  __syncthreads();
  int nb = btot[b];
  const unsigned int* bp = buck + (size_t)b * BCAP;
  for (int i = t; i < nb; i += 256) {
    unsigned int p = bp[i];
    int dl = (int)(p >> 17);
    int node = b * 128 + dl;
    int l = atomicAdd(&cnt[dl], 1);
    csr_src[row_start[node] + l] = (int)(p & 0x1FFFFu);
  }
}

// ---------------- BN constants, both layers in one dispatch ----------------
__global__ void k_prep_bn2(const float* __restrict__ b1, const float* __restrict__ g1,
                           const float* __restrict__ be1, const float* __restrict__ m1,
                           const float* __restrict__ v1,
                           const float* __restrict__ b2, const float* __restrict__ g2,
                           const float* __restrict__ be2, const float* __restrict__ m2,
                           const float* __restrict__ v2,
                           float* __restrict__ sc1, float* __restrict__ sh1,
                           float* __restrict__ sc2, float* __restrict__ sh2) {
  int t = threadIdx.x;
  if (t < FD) {
    float s = g1[t] * rsqrtf(v1[t] + BN_EPS);
    sc1[t] = s;
    sh1[t] = (b1[t] - m1[t]) * s + be1[t];
  } else {
    int f = t - FD;
    float s = g2[f] * rsqrtf(v2[f] + BN_EPS);
    sc2[f] = s;
    sh2[f] = (b2[f] - m2[f]) * s + be2[f];
  }
}

// ---------------- MFMA GEMM 128x128 (bf16x3 split) -> pre-scaled bf16 rows ----
__global__ __launch_bounds__(256) void k_gemm128_mfma(const float* __restrict__ X,
                                                      const float* __restrict__ W,
                                                      const float* __restrict__ dinv,
                                                      unsigned short* __restrict__ Hbs,
                                                      int nrows) {
  __shared__ short bhi_s[FD * FD];  // 32 KB
  __shared__ short blo_s[FD * FD];  // 32 KB
  int tid = threadIdx.x;
  for (int i = tid; i < FD * FD; i += 256) {
    int k = i >> 7, n = i & 127;
    float w = W[i];
    unsigned short h = f2bf(w);
    unsigned short l = f2bf(w - bf2f(h));
    int idx = ((((k >> 5) * 8) + (n >> 4)) * 64 + ((k >> 3) & 3) * 16 + (n & 15)) * 8 + (k & 7);
    bhi_s[idx] = (short)h;
    blo_s[idx] = (short)l;
  }

  int lane = tid & 63, wv = tid >> 6;
  int lg = lane >> 4, li = lane & 15;
  int wr0 = blockIdx.x * 64 + wv * 16;
  int row = wr0 + li;
  bool ok = row < nrows;

  short8 ahi[4], alo[4];
#pragma unroll
  for (int ks = 0; ks < 4; ++ks) {
    if (ok) {
      const float* xp = X + (size_t)row * FD + ks * 32 + lg * 8;
      float4 v0 = *(const float4*)xp;
      float4 v1 = *(const float4*)(xp + 4);
      float f[8] = {v0.x, v0.y, v0.z, v0.w, v1.x, v1.y, v1.z, v1.w};
#pragma unroll
      for (int j = 0; j < 8; ++j) {
        unsigned short h = f2bf(f[j]);
        ahi[ks][j] = (short)h;
        alo[ks][j] = (short)f2bf(f[j] - bf2f(h));
      }
    } else {
#pragma unroll
      for (int j = 0; j < 8; ++j) { ahi[ks][j] = 0; alo[ks][j] = 0; }
    }
  }
  __syncthreads();

  int rb = wr0 + lg * 4;
  float dvr[4];
#pragma unroll
  for (int r = 0; r < 4; ++r) dvr[r] = (rb + r < nrows) ? dinv[rb + r] : 0.f;

#pragma unroll
  for (int nt = 0; nt < 8; ++nt) {
    f32x4 acc = {0.f, 0.f, 0.f, 0.f};
#pragma unroll
    for (int ks = 0; ks < 4; ++ks) {
      int bidx = ((ks * 8 + nt) * 64 + lane) * 8;
      short8 bh = *(const short8*)&bhi_s[bidx];
      short8 bl = *(const short8*)&blo_s[bidx];
      acc = __builtin_amdgcn_mfma_f32_16x16x32_bf16(ahi[ks], bh, acc, 0, 0, 0);
      acc = __builtin_amdgcn_mfma_f32_16x16x32_bf16(alo[ks], bh, acc, 0, 0, 0);
      acc = __builtin_amdgcn_mfma_f32_16x16x32_bf16(ahi[ks], bl, acc, 0, 0, 0);
    }
    // C/D: col = lane&15, row = (lane>>4)*4 + reg   [m89-verified]
    int col = nt * 16 + li;
#pragma unroll
    for (int r = 0; r < 4; ++r) {
      if (rb + r < nrows)
        Hbs[(size_t)(rb + r) * FD + col] = f2bf(acc[r] * dvr[r]);
    }
  }
}

// ---------------- node-parallel gather over pre-scaled bf16 rows ------------
// 8 independent accumulator chains; tail folds into chain 0 (static indices).
template <bool BN>
__global__ __launch_bounds__(256) void k_gather128(const int* __restrict__ row_start,
                                                   const int* __restrict__ csr_src,
                                                   const float* __restrict__ dinv,
                                                   const unsigned short* __restrict__ Hbs,
                                                   const float* __restrict__ sc,
                                                   const float* __restrict__ sh,
                                                   float* __restrict__ AGG) {
  int node = blockIdx.x * 4 + (threadIdx.x >> 6);
  if (node >= NN) return;
  int lane = threadIdx.x & 63;
  const unsigned int* Hc = (const unsigned int*)Hbs;  // [N][64] packed bf16x2
  int beg = row_start[node], end = row_start[node + 1];
  float px0 = 0.f, px1 = 0.f, px2 = 0.f, px3 = 0.f;
  float px4 = 0.f, px5 = 0.f, px6 = 0.f, px7 = 0.f;
  float py0 = 0.f, py1 = 0.f, py2 = 0.f, py3 = 0.f;
  float py4 = 0.f, py5 = 0.f, py6 = 0.f, py7 = 0.f;
  {
    unsigned int us = Hc[(size_t)node * 64 + lane];   // self row (pre-scaled)
    px0 = blo(us); py0 = bhi(us);
  }
  int e = beg;
  for (; e + 7 < end; e += 8) {
    unsigned int u0 = Hc[(size_t)csr_src[e + 0] * 64 + lane];
    unsigned int u1 = Hc[(size_t)csr_src[e + 1] * 64 + lane];
    unsigned int u2 = Hc[(size_t)csr_src[e + 2] * 64 + lane];
    unsigned int u3 = Hc[(size_t)csr_src[e + 3] * 64 + lane];
    unsigned int u4 = Hc[(size_t)csr_src[e + 4] * 64 + lane];
    unsigned int u5 = Hc[(size_t)csr_src[e + 5] * 64 + lane];
    unsigned int u6 = Hc[(size_t)csr_src[e + 6] * 64 + lane];
    unsigned int u7 = Hc[(size_t)csr_src[e + 7] * 64 + lane];
    px0 += blo(u0); py0 += bhi(u0);
    px1 += blo(u1); py1 += bhi(u1);
    px2 += blo(u2); py2 += bhi(u2);
    px3 += blo(u3); py3 += bhi(u3);
    px4 += blo(u4); py4 += bhi(u4);
    px5 += blo(u5); py5 += bhi(u5);
    px6 += blo(u6); py6 += bhi(u6);
    px7 += blo(u7); py7 += bhi(u7);
  }
  for (; e < end; ++e) {
    unsigned int u0 = Hc[(size_t)csr_src[e] * 64 + lane];
    px0 += blo(u0); py0 += bhi(u0);
  }
  float dv = dinv[node];
  float accx = (((px0 + px1) + (px2 + px3)) + ((px4 + px5) + (px6 + px7))) * dv;
  float accy = (((py0 + py1) + (py2 + py3)) + ((py4 + py5) + (py6 + py7))) * dv;
  if (BN) {
    float scx = sc[lane * 2], scy = sc[lane * 2 + 1];
    float shx = sh[lane * 2], shy = sh[lane * 2 + 1];
    accx = fmaxf(fmaf(accx, scx, shx), 0.f);
    accy = fmaxf(fmaf(accy, scy, shy), 0.f);
  }
  float2 o; o.x = accx; o.y = accy;
  ((float2*)(AGG + (size_t)node * FD))[lane] = o;
}

// ---------------- output GEMM 128->10 ----------------
__global__ __launch_bounds__(256) void k_gemm_out(const float* __restrict__ X,
                                                  const float* __restrict__ W3,
                                                  float* __restrict__ H3, int nrows) {
  __shared__ float ws[FD * 16];
  int tid = threadIdx.x;
  for (int i = tid; i < FD * 16; i += 256) {
    int k = i >> 4, c = i & 15;
    ws[i] = (c < CO) ? W3[k * CO + c] : 0.f;
  }
  __syncthreads();
  int grp = tid >> 4;
  int c = tid & 15;
  int r = blockIdx.x * 16 + grp;
  if (r >= nrows) return;
  const float* x = X + (size_t)r * FD;
  float acc = 0.f;
#pragma unroll
  for (int k = 0; k < FD; k += 4) {
    float4 xv = *(const float4*)&x[k];
    acc += xv.x * ws[(k + 0) * 16 + c];
    acc += xv.y * ws[(k + 1) * 16 + c];
    acc += xv.z * ws[(k + 2) * 16 + c];
    acc += xv.w * ws[(k + 3) * 16 + c];
  }
  if (c < CO) H3[(size_t)r * CO + c] = acc;
}

// ---------------- gather 10 feat, fused self-loop + bias, writes out --------
__global__ __launch_bounds__(256) void k_gather10(const int* __restrict__ row_start,
                                                  const int* __restrict__ csr_src,
                                                  const float* __restrict__ dinv,
                                                  const float* __restrict__ H3,
                                                  const float* __restrict__ b3,
                                                  float* __restrict__ out) {
  int node = blockIdx.x * 16 + (threadIdx.x >> 4);
  if (node >= NN) return;
  int c = threadIdx.x & 15;
  int beg = row_start[node], end = row_start[node + 1];
  float dv = dinv[node];
  float acc = 0.f;
  if (c < CO) acc = H3[(size_t)node * CO + c] * (dv * dv);
  for (int e = beg; e < end; ++e) {
    int s = csr_src[e];
    float cf = dinv[s] * dv;
    if (c < CO) acc = fmaf(H3[(size_t)s * CO + c], cf, acc);
  }
  if (c < CO) out[(size_t)node * CO + c] = acc + b3[c];
}

// ---------------- launch ----------------
extern "C" void kernel_launch(void* const* d_in, const int* in_sizes, int n_in,
                              void* d_out, int out_size, void* d_ws, size_t ws_size,
                              hipStream_t stream) {
  const float* x = (const float*)d_in[0];
  const int* src = (const int*)d_in[1];
  const int* dst = (const int*)d_in[2];
  const float* W1 = (const float*)d_in[3];
  const float* b1 = (const float*)d_in[4];
  const float* g1 = (const float*)d_in[5];
  const float* be1 = (const float*)d_in[6];
  const float* m1 = (const float*)d_in[7];
  const float* v1 = (const float*)d_in[8];
  const float* W2 = (const float*)d_in[9];
  const float* b2 = (const float*)d_in[10];
  const float* g2 = (const float*)d_in[11];
  const float* be2 = (const float*)d_in[12];
  const float* m2 = (const float*)d_in[13];
  const float* v2 = (const float*)d_in[14];
  const float* W3 = (const float*)d_in[15];
  const float* b3 = (const float*)d_in[16];
  float* out = (float*)d_out;

  char* wsb = (char*)d_ws;
  int* deg_i = (int*)wsb;                     wsb += NN * 4;
  int* row_start = (int*)wsb;                 wsb += (NN + 1) * 4;
  int* histM = (int*)wsb;                     wsb += (size_t)NSEG * NBUKP * 4;
  int* segbase = (int*)wsb;                   wsb += (size_t)NSEG * NBUKP * 4;
  int* btot = (int*)wsb;                      wsb += NBUKP * 4;
  int* blocksum = (int*)wsb;                  wsb += 128 * 4;
  float* dinv = (float*)wsb;                  wsb += NN * 4;
  float* sc1 = (float*)wsb;                   wsb += FD * 4;
  float* sh1 = (float*)wsb;                   wsb += FD * 4;
  float* sc2 = (float*)wsb;                   wsb += FD * 4;
  float* sh2 = (float*)wsb;                   wsb += FD * 4;
  int* csr_src = (int*)wsb;                   wsb += (size_t)NE * 4;
  unsigned int* buck = (unsigned int*)wsb;    wsb += (size_t)NBUK * BCAP * 4;
  float* AGG = (float*)wsb;                   wsb += (size_t)NN * FD * 4;   // [N][128] f32
  unsigned short* Hbs = (unsigned short*)wsb; wsb += (size_t)NN * FD * 2;   // [N][128] bf16
  float* H3 = (float*)Hbs;  // layer-3 reuse (Hbs dead after layer-2 gather)

  k_hist<<<NSEG, 256, 0, stream>>>(dst, histM);
  k_colscan<<<(NBUK + 255) / 256, 256, 0, stream>>>(histM, segbase, btot);
  k_scatter2<<<NSEG, 256, 0, stream>>>(src, dst, segbase, buck);
  k_bdeg<<<NBUK, 256, 0, stream>>>(btot, buck, deg_i, dinv);
  k_scan_partial<<<SCAN_NB, 256, 0, stream>>>(deg_i, blocksum);
  k_scan_block<<<1, 128, 0, stream>>>(blocksum);
  k_scan_final<<<SCAN_NB, 256, 0, stream>>>(deg_i, blocksum, row_start);
  k_place<<<NBUK, 256, 0, stream>>>(btot, buck, row_start, csr_src);
  k_prep_bn2<<<1, 256, 0, stream>>>(b1, g1, be1, m1, v1, b2, g2, be2, m2, v2,
                                    sc1, sh1, sc2, sh2);

  int gemm_blocks = (NN + 63) / 64;
  int gat_blocks = (NN + 3) / 4;

  // layer 1
  k_gemm128_mfma<<<gemm_blocks, 256, 0, stream>>>(x, W1, dinv, Hbs, NN);
  k_gather128<true><<<gat_blocks, 256, 0, stream>>>(row_start, csr_src, dinv,
                                                    Hbs, sc1, sh1, AGG);
  // layer 2
  k_gemm128_mfma<<<gemm_blocks, 256, 0, stream>>>(AGG, W2, dinv, Hbs, NN);
  k_gather128<true><<<gat_blocks, 256, 0, stream>>>(row_start, csr_src, dinv,
                                                    Hbs, sc2, sh2, AGG);
  // layer 3
  k_gemm_out<<<(NN + 15) / 16, 256, 0, stream>>>(AGG, W3, H3, NN);
  k_gather10<<<(NN + 15) / 16, 256, 0, stream>>>(row_start, csr_src, dinv,
                                                 H3, b3, out);
}

// Round 11
// 374.977 us; speedup vs baseline: 1.1978x; 1.1978x over previous
//
#include <hip/hip_runtime.h>

#define NN 100000
#define NE 1600000
#define FD 128
#define CO 10
#define BN_EPS 1e-5f
#define SCAN_B 1024
#define SCAN_NB ((NN + SCAN_B - 1) / SCAN_B)   // 98
#define NBUK ((NN + 127) / 128)                // 782 buckets of 128 nodes
#define NBUKP 784
#define BCAP 3072
#define SEGE 4096
#define NSEG ((NE + SEGE - 1) / SEGE)          // 391

typedef __attribute__((ext_vector_type(8))) short short8;
typedef __attribute__((ext_vector_type(4))) float f32x4;

__device__ __forceinline__ unsigned short f2bf(float f) {
  unsigned int u = __builtin_bit_cast(unsigned int, f);
  u = (u + 0x7FFFu + ((u >> 16) & 1u)) >> 16;
  return (unsigned short)u;
}
__device__ __forceinline__ float bf2f(unsigned short h) {
  unsigned int u = ((unsigned int)h) << 16;
  return __builtin_bit_cast(float, u);
}
__device__ __forceinline__ float blo(unsigned int u) {
  return __builtin_bit_cast(float, u << 16);
}
__device__ __forceinline__ float bhi(unsigned int u) {
  return __builtin_bit_cast(float, u & 0xFFFF0000u);
}

// ---------------- pass 1: per-segment bucket histogram ----------------
__global__ __launch_bounds__(256) void k_hist(const int* __restrict__ dst,
                                              int* __restrict__ histM) {
  __shared__ int hist[NBUK];
  int b = blockIdx.x, t = threadIdx.x;
  for (int i = t; i < NBUK; i += 256) hist[i] = 0;
  __syncthreads();
  int e0 = b * SEGE, e1 = min(e0 + SEGE, NE);
  for (int e = e0 + t; e < e1; e += 256) atomicAdd(&hist[dst[e] >> 7], 1);
  __syncthreads();
  for (int i = t; i < NBUK; i += 256) histM[b * NBUKP + i] = hist[i];
}

// ---------------- pass 2: per-bucket prefix over segments (parallel) --------
// One block per bucket: LDS scan over NSEG=391 entries.
__global__ __launch_bounds__(256) void k_colscan(const int* __restrict__ histM,
                                                 int* __restrict__ segbase,
                                                 int* __restrict__ btot) {
  __shared__ int lds[256];
  int b = blockIdx.x, t = threadIdx.x;
  // each thread sums 2 segs (391 <= 512)
  int s0 = t * 2, s1 = t * 2 + 1;
  int v0 = (s0 < NSEG) ? histM[s0 * NBUKP + b] : 0;
  int v1 = (s1 < NSEG) ? histM[s1 * NBUKP + b] : 0;
  int pair = v0 + v1;
  lds[t] = pair;
  __syncthreads();
  int mine = pair;
  for (int off = 1; off < 256; off <<= 1) {
    int add = (t >= off) ? lds[t - off] : 0;
    __syncthreads();
    lds[t] += add;
    __syncthreads();
  }
  int run = lds[t] - mine;  // exclusive over pairs
  if (s0 < NSEG) segbase[s0 * NBUKP + b] = run;
  if (s1 < NSEG) segbase[s1 * NBUKP + b] = run + v0;
  if (t == 255) btot[b] = lds[255];
}

// ---------------- pass 3: scatter into buckets, LDS cursors, packed u32 ------
__global__ __launch_bounds__(256) void k_scatter2(const int* __restrict__ src,
                                                  const int* __restrict__ dst,
                                                  const int* __restrict__ segbase,
                                                  unsigned int* __restrict__ buck) {
  __shared__ int base[NBUK];
  int b = blockIdx.x, t = threadIdx.x;
  for (int i = t; i < NBUK; i += 256) base[i] = segbase[b * NBUKP + i];
  __syncthreads();
  int e0 = b * SEGE, e1 = min(e0 + SEGE, NE);
  for (int e = e0 + t; e < e1; e += 256) {
    int s = src[e], d = dst[e];
    int bk = d >> 7;
    int slot = atomicAdd(&base[bk], 1);
    buck[(size_t)bk * BCAP + slot] = ((unsigned int)(d & 127) << 17) | (unsigned int)s;
  }
}

// ---------------- per-bucket degree count + fused dinv ----------------
__global__ __launch_bounds__(256) void k_bdeg(const int* __restrict__ btot,
                                              const unsigned int* __restrict__ buck,
                                              int* __restrict__ deg_i,
                                              float* __restrict__ dinv) {
  __shared__ int cnt[128];
  int b = blockIdx.x, t = threadIdx.x;
  if (t < 128) cnt[t] = 0;
  __syncthreads();
  int nb = btot[b];
  const unsigned int* bp = buck + (size_t)b * BCAP;
  for (int i = t; i < nb; i += 256) atomicAdd(&cnt[bp[i] >> 17], 1);
  __syncthreads();
  int node = b * 128 + t;
  if (t < 128 && node < NN) {
    int dg = cnt[t];
    deg_i[node] = dg;
    dinv[node] = rsqrtf((float)dg + 1.0f);
  }
}

// ---------------- exclusive scan over deg_i -> row_start ----------------
__global__ __launch_bounds__(256) void k_scan_partial(const int* __restrict__ deg_i,
                                                      int* __restrict__ blocksum) {
  __shared__ int lds[256];
  int b = blockIdx.x, t = threadIdx.x;
  int base = b * SCAN_B + t * 4;
  int s = 0;
#pragma unroll
  for (int i = 0; i < 4; ++i) {
    int idx = base + i;
    s += (idx < NN) ? deg_i[idx] : 0;
  }
  lds[t] = s;
  __syncthreads();
  for (int off = 128; off > 0; off >>= 1) {
    if (t < off) lds[t] += lds[t + off];
    __syncthreads();
  }
  if (t == 0) blocksum[b] = lds[0];
}

__global__ void k_scan_block(int* __restrict__ blocksum) {
  __shared__ int lds[128];
  int t = threadIdx.x;
  int v = (t < SCAN_NB) ? blocksum[t] : 0;
  lds[t] = v;
  __syncthreads();
  for (int off = 1; off < 128; off <<= 1) {
    int add = (t >= off) ? lds[t - off] : 0;
    __syncthreads();
    lds[t] += add;
    __syncthreads();
  }
  if (t < SCAN_NB) blocksum[t] = lds[t] - v;
}

__global__ __launch_bounds__(256) void k_scan_final(const int* __restrict__ deg_i,
                                                    const int* __restrict__ blocksum,
                                                    int* __restrict__ row_start) {
  __shared__ int lds[256];
  int b = blockIdx.x, t = threadIdx.x;
  int base = b * SCAN_B + t * 4;
  int v[4];
  int s = 0;
#pragma unroll
  for (int i = 0; i < 4; ++i) {
    int idx = base + i;
    v[i] = (idx < NN) ? deg_i[idx] : 0;
    s += v[i];
  }
  lds[t] = s;
  __syncthreads();
  int mine = s;
  for (int off = 1; off < 256; off <<= 1) {
    int add = (t >= off) ? lds[t - off] : 0;
    __syncthreads();
    lds[t] += add;
    __syncthreads();
  }
  int run = lds[t] - mine + blocksum[b];
#pragma unroll
  for (int i = 0; i < 4; ++i) {
    int idx = base + i;
    if (idx < NN) {
      row_start[idx] = run;
      run += v[i];
    }
  }
  if (b == 0 && t == 0) row_start[NN] = NE;
}

// ---------------- place pass: bucket -> CSR ----------------
__global__ __launch_bounds__(256) void k_place(const int* __restrict__ btot,
                                               const unsigned int* __restrict__ buck,
                                               const int* __restrict__ row_start,
                                               int* __restrict__ csr_src) {
  __shared__ int cnt[128];
  int b = blockIdx.x, t = threadIdx.x;
  if (t < 128) cnt[t] = 0;
  __syncthreads();
  int nb = btot[b];
  const unsigned int* bp = buck + (size_t)b * BCAP;
  for (int i = t; i < nb; i += 256) {
    unsigned int p = bp[i];
    int dl = (int)(p >> 17);
    int node = b * 128 + dl;
    int l = atomicAdd(&cnt[dl], 1);
    csr_src[row_start[node] + l] = (int)(p & 0x1FFFFu);
  }
}

// ---------------- fused setup: W1/W2 -> fragment-ordered bf16 hi/lo + BN ----
// blocks 0..63: W1; 64..127: W2; 128: BN constants.
__global__ __launch_bounds__(256) void k_prep(const float* __restrict__ W1,
                                              const float* __restrict__ W2,
                                              unsigned short* __restrict__ w1hi,
                                              unsigned short* __restrict__ w1lo,
                                              unsigned short* __restrict__ w2hi,
                                              unsigned short* __restrict__ w2lo,
                                              const float* __restrict__ b1, const float* __restrict__ g1,
                                              const float* __restrict__ be1, const float* __restrict__ m1,
                                              const float* __restrict__ v1,
                                              const float* __restrict__ b2, const float* __restrict__ g2,
                                              const float* __restrict__ be2, const float* __restrict__ m2,
                                              const float* __restrict__ v2,
                                              float* __restrict__ sc1, float* __restrict__ sh1,
                                              float* __restrict__ sc2, float* __restrict__ sh2) {
  int b = blockIdx.x, t = threadIdx.x;
  if (b < 128) {
    const float* W = (b < 64) ? W1 : W2;
    unsigned short* whi = (b < 64) ? w1hi : w2hi;
    unsigned short* wlo = (b < 64) ? w1lo : w2lo;
    int i = ((b & 63) * 256 + t);
    int k = i >> 7, n = i & 127;
    float w = W[i];
    unsigned short h = f2bf(w);
    unsigned short l = f2bf(w - bf2f(h));
    int idx = ((((k >> 5) * 8) + (n >> 4)) * 64 + ((k >> 3) & 3) * 16 + (n & 15)) * 8 + (k & 7);
    whi[idx] = h;
    wlo[idx] = l;
  } else {
    if (t < FD) {
      float s = g1[t] * rsqrtf(v1[t] + BN_EPS);
      sc1[t] = s;
      sh1[t] = (b1[t] - m1[t]) * s + be1[t];
    } else if (t < 2 * FD) {
      int f = t - FD;
      float s = g2[f] * rsqrtf(v2[f] + BN_EPS);
      sc2[f] = s;
      sh2[f] = (b2[f] - m2[f]) * s + be2[f];
    }
  }
}

// ---------------- LDS-free MFMA GEMM 128x128 -> pre-scaled bf16 rows --------
// B-fragments read straight from global (L2-hot, same addrs for all blocks).
__global__ __launch_bounds__(256) void k_gemm128_mfma(const float* __restrict__ X,
                                                      const unsigned short* __restrict__ whi,
                                                      const unsigned short* __restrict__ wlo,
                                                      const float* __restrict__ dinv,
                                                      unsigned short* __restrict__ Hbs,
                                                      int nrows) {
  int tid = threadIdx.x;
  int lane = tid & 63, wv = tid >> 6;
  int lg = lane >> 4, li = lane & 15;
  int wr0 = blockIdx.x * 64 + wv * 16;
  int row = wr0 + li;
  bool ok = row < nrows;

  short8 ahi[4], alo[4];
#pragma unroll
  for (int ks = 0; ks < 4; ++ks) {
    if (ok) {
      const float* xp = X + (size_t)row * FD + ks * 32 + lg * 8;
      float4 v0 = *(const float4*)xp;
      float4 v1 = *(const float4*)(xp + 4);
      float f[8] = {v0.x, v0.y, v0.z, v0.w, v1.x, v1.y, v1.z, v1.w};
#pragma unroll
      for (int j = 0; j < 8; ++j) {
        unsigned short h = f2bf(f[j]);
        ahi[ks][j] = (short)h;
        alo[ks][j] = (short)f2bf(f[j] - bf2f(h));
      }
    } else {
#pragma unroll
      for (int j = 0; j < 8; ++j) { ahi[ks][j] = 0; alo[ks][j] = 0; }
    }
  }

  int rb = wr0 + lg * 4;
  float dvr[4];
#pragma unroll
  for (int r = 0; r < 4; ++r) dvr[r] = (rb + r < nrows) ? dinv[rb + r] : 0.f;

#pragma unroll
  for (int nt = 0; nt < 8; ++nt) {
    f32x4 acc = {0.f, 0.f, 0.f, 0.f};
#pragma unroll
    for (int ks = 0; ks < 4; ++ks) {
      int bidx = ((ks * 8 + nt) * 64 + lane) * 8;
      short8 bh = *(const short8*)&whi[bidx];
      short8 bl = *(const short8*)&wlo[bidx];
      acc = __builtin_amdgcn_mfma_f32_16x16x32_bf16(ahi[ks], bh, acc, 0, 0, 0);
      acc = __builtin_amdgcn_mfma_f32_16x16x32_bf16(alo[ks], bh, acc, 0, 0, 0);
      acc = __builtin_amdgcn_mfma_f32_16x16x32_bf16(ahi[ks], bl, acc, 0, 0, 0);
    }
    // C/D: col = lane&15, row = (lane>>4)*4 + reg   [m89-verified]
    int col = nt * 16 + li;
#pragma unroll
    for (int r = 0; r < 4; ++r) {
      if (rb + r < nrows)
        Hbs[(size_t)(rb + r) * FD + col] = f2bf(acc[r] * dvr[r]);
    }
  }
}

// ---------------- node-parallel gather over pre-scaled bf16 rows ------------
template <bool BN>
__global__ __launch_bounds__(256) void k_gather128(const int* __restrict__ row_start,
                                                   const int* __restrict__ csr_src,
                                                   const float* __restrict__ dinv,
                                                   const unsigned short* __restrict__ Hbs,
                                                   const float* __restrict__ sc,
                                                   const float* __restrict__ sh,
                                                   float* __restrict__ AGG) {
  int node = blockIdx.x * 4 + (threadIdx.x >> 6);
  if (node >= NN) return;
  int lane = threadIdx.x & 63;
  const unsigned int* Hc = (const unsigned int*)Hbs;  // [N][64] packed bf16x2
  int beg = row_start[node], end = row_start[node + 1];
  float px0 = 0.f, px1 = 0.f, px2 = 0.f, px3 = 0.f;
  float py0 = 0.f, py1 = 0.f, py2 = 0.f, py3 = 0.f;
  {
    unsigned int us = Hc[(size_t)node * 64 + lane];   // self row (pre-scaled)
    px0 = blo(us); py0 = bhi(us);
  }
  int e = beg;
  for (; e + 3 < end; e += 4) {
    unsigned int u0 = Hc[(size_t)csr_src[e + 0] * 64 + lane];
    unsigned int u1 = Hc[(size_t)csr_src[e + 1] * 64 + lane];
    unsigned int u2 = Hc[(size_t)csr_src[e + 2] * 64 + lane];
    unsigned int u3 = Hc[(size_t)csr_src[e + 3] * 64 + lane];
    px0 += blo(u0); py0 += bhi(u0);
    px1 += blo(u1); py1 += bhi(u1);
    px2 += blo(u2); py2 += bhi(u2);
    px3 += blo(u3); py3 += bhi(u3);
  }
  for (; e < end; ++e) {
    unsigned int u0 = Hc[(size_t)csr_src[e] * 64 + lane];
    px0 += blo(u0); py0 += bhi(u0);
  }
  float dv = dinv[node];
  float accx = ((px0 + px1) + (px2 + px3)) * dv;
  float accy = ((py0 + py1) + (py2 + py3)) * dv;
  if (BN) {
    float scx = sc[lane * 2], scy = sc[lane * 2 + 1];
    float shx = sh[lane * 2], shy = sh[lane * 2 + 1];
    accx = fmaxf(fmaf(accx, scx, shx), 0.f);
    accy = fmaxf(fmaf(accy, scy, shy), 0.f);
  }
  float2 o; o.x = accx; o.y = accy;
  ((float2*)(AGG + (size_t)node * FD))[lane] = o;
}

// ---------------- output GEMM 128->10 ----------------
__global__ __launch_bounds__(256) void k_gemm_out(const float* __restrict__ X,
                                                  const float* __restrict__ W3,
                                                  float* __restrict__ H3, int nrows) {
  __shared__ float ws[FD * 16];
  int tid = threadIdx.x;
  for (int i = tid; i < FD * 16; i += 256) {
    int k = i >> 4, c = i & 15;
    ws[i] = (c < CO) ? W3[k * CO + c] : 0.f;
  }
  __syncthreads();
  int grp = tid >> 4;
  int c = tid & 15;
  int r = blockIdx.x * 16 + grp;
  if (r >= nrows) return;
  const float* x = X + (size_t)r * FD;
  float acc = 0.f;
#pragma unroll
  for (int k = 0; k < FD; k += 4) {
    float4 xv = *(const float4*)&x[k];
    acc += xv.x * ws[(k + 0) * 16 + c];
    acc += xv.y * ws[(k + 1) * 16 + c];
    acc += xv.z * ws[(k + 2) * 16 + c];
    acc += xv.w * ws[(k + 3) * 16 + c];
  }
  if (c < CO) H3[(size_t)r * CO + c] = acc;
}

// ---------------- gather 10 feat, fused self-loop + bias, writes out --------
__global__ __launch_bounds__(256) void k_gather10(const int* __restrict__ row_start,
                                                  const int* __restrict__ csr_src,
                                                  const float* __restrict__ dinv,
                                                  const float* __restrict__ H3,
                                                  const float* __restrict__ b3,
                                                  float* __restrict__ out) {
  int node = blockIdx.x * 16 + (threadIdx.x >> 4);
  if (node >= NN) return;
  int c = threadIdx.x & 15;
  int beg = row_start[node], end = row_start[node + 1];
  float dv = dinv[node];
  float acc = 0.f;
  if (c < CO) acc = H3[(size_t)node * CO + c] * (dv * dv);
  for (int e = beg; e < end; ++e) {
    int s = csr_src[e];
    float cf = dinv[s] * dv;
    if (c < CO) acc = fmaf(H3[(size_t)s * CO + c], cf, acc);
  }
  if (c < CO) out[(size_t)node * CO + c] = acc + b3[c];
}

// ---------------- launch ----------------
extern "C" void kernel_launch(void* const* d_in, const int* in_sizes, int n_in,
                              void* d_out, int out_size, void* d_ws, size_t ws_size,
                              hipStream_t stream) {
  const float* x = (const float*)d_in[0];
  const int* src = (const int*)d_in[1];
  const int* dst = (const int*)d_in[2];
  const float* W1 = (const float*)d_in[3];
  const float* b1 = (const float*)d_in[4];
  const float* g1 = (const float*)d_in[5];
  const float* be1 = (const float*)d_in[6];
  const float* m1 = (const float*)d_in[7];
  const float* v1 = (const float*)d_in[8];
  const float* W2 = (const float*)d_in[9];
  const float* b2 = (const float*)d_in[10];
  const float* g2 = (const float*)d_in[11];
  const float* be2 = (const float*)d_in[12];
  const float* m2 = (const float*)d_in[13];
  const float* v2 = (const float*)d_in[14];
  const float* W3 = (const float*)d_in[15];
  const float* b3 = (const float*)d_in[16];
  float* out = (float*)d_out;

  char* wsb = (char*)d_ws;
  int* deg_i = (int*)wsb;                     wsb += NN * 4;
  int* row_start = (int*)wsb;                 wsb += (NN + 1) * 4;
  int* histM = (int*)wsb;                     wsb += (size_t)NSEG * NBUKP * 4;
  int* segbase = (int*)wsb;                   wsb += (size_t)NSEG * NBUKP * 4;
  int* btot = (int*)wsb;                      wsb += NBUKP * 4;
  int* blocksum = (int*)wsb;                  wsb += 128 * 4;
  float* dinv = (float*)wsb;                  wsb += NN * 4;
  float* sc1 = (float*)wsb;                   wsb += FD * 4;
  float* sh1 = (float*)wsb;                   wsb += FD * 4;
  float* sc2 = (float*)wsb;                   wsb += FD * 4;
  float* sh2 = (float*)wsb;                   wsb += FD * 4;
  unsigned short* w1hi = (unsigned short*)wsb; wsb += FD * FD * 2;
  unsigned short* w1lo = (unsigned short*)wsb; wsb += FD * FD * 2;
  unsigned short* w2hi = (unsigned short*)wsb; wsb += FD * FD * 2;
  unsigned short* w2lo = (unsigned short*)wsb; wsb += FD * FD * 2;
  int* csr_src = (int*)wsb;                   wsb += (size_t)NE * 4;
  unsigned int* buck = (unsigned int*)wsb;    wsb += (size_t)NBUK * BCAP * 4;
  float* AGG = (float*)wsb;                   wsb += (size_t)NN * FD * 4;   // [N][128] f32
  unsigned short* Hbs = (unsigned short*)wsb; wsb += (size_t)NN * FD * 2;   // [N][128] bf16
  float* H3 = (float*)Hbs;  // layer-3 reuse (Hbs dead after layer-2 gather)

  k_hist<<<NSEG, 256, 0, stream>>>(dst, histM);
  k_colscan<<<NBUK, 256, 0, stream>>>(histM, segbase, btot);
  k_scatter2<<<NSEG, 256, 0, stream>>>(src, dst, segbase, buck);
  k_bdeg<<<NBUK, 256, 0, stream>>>(btot, buck, deg_i, dinv);
  k_scan_partial<<<SCAN_NB, 256, 0, stream>>>(deg_i, blocksum);
  k_scan_block<<<1, 128, 0, stream>>>(blocksum);
  k_scan_final<<<SCAN_NB, 256, 0, stream>>>(deg_i, blocksum, row_start);
  k_place<<<NBUK, 256, 0, stream>>>(btot, buck, row_start, csr_src);
  k_prep<<<129, 256, 0, stream>>>(W1, W2, w1hi, w1lo, w2hi, w2lo,
                                  b1, g1, be1, m1, v1, b2, g2, be2, m2, v2,
                                  sc1, sh1, sc2, sh2);

  int gemm_blocks = (NN + 63) / 64;
  int gat_blocks = (NN + 3) / 4;

  // layer 1
  k_gemm128_mfma<<<gemm_blocks, 256, 0, stream>>>(x, w1hi, w1lo, dinv, Hbs, NN);
  k_gather128<true><<<gat_blocks, 256, 0, stream>>>(row_start, csr_src, dinv,
                                                    Hbs, sc1, sh1, AGG);
  // layer 2
  k_gemm128_mfma<<<gemm_blocks, 256, 0, stream>>>(AGG, w2hi, w2lo, dinv, Hbs, NN);
  k_gather128<true><<<gat_blocks, 256, 0, stream>>>(row_start, csr_src, dinv,
                                                    Hbs, sc2, sh2, AGG);
  // layer 3
  k_gemm_out<<<(NN + 15) / 16, 256, 0, stream>>>(AGG, W3, H3, NN);
  k_gather10<<<(NN + 15) / 16, 256, 0, stream>>>(row_start, csr_src, dinv,
                                                 H3, b3, out);
}

// Round 12
// 357.010 us; speedup vs baseline: 1.2581x; 1.0503x over previous
//
#include <hip/hip_runtime.h>

#define NN 100000
#define NE 1600000
#define FD 128
#define CO 10
#define BN_EPS 1e-5f
#define NBUK ((NN + 127) / 128)                // 782 buckets of 128 nodes
#define NBUKP 784
#define BCAP 3072
#define SEGE 4096
#define NSEG ((NE + SEGE - 1) / SEGE)          // 391

typedef __attribute__((ext_vector_type(8))) short short8;
typedef __attribute__((ext_vector_type(4))) float f32x4;

__device__ __forceinline__ unsigned short f2bf(float f) {
  unsigned int u = __builtin_bit_cast(unsigned int, f);
  u = (u + 0x7FFFu + ((u >> 16) & 1u)) >> 16;
  return (unsigned short)u;
}
__device__ __forceinline__ float bf2f(unsigned short h) {
  unsigned int u = ((unsigned int)h) << 16;
  return __builtin_bit_cast(float, u);
}
__device__ __forceinline__ float blo(unsigned int u) {
  return __builtin_bit_cast(float, u << 16);
}
__device__ __forceinline__ float bhi(unsigned int u) {
  return __builtin_bit_cast(float, u & 0xFFFF0000u);
}
// packed bf16 convert: D[15:0]=bf16(a), D[31:16]=bf16(b)  [RNE, gfx950]
__device__ __forceinline__ unsigned int cvt_pk_bf16(float a, float b) {
  unsigned int r;
  asm("v_cvt_pk_bf16_f32 %0, %1, %2" : "=v"(r) : "v"(a), "v"(b));
  return r;
}

// ---------------- pass 1: per-segment bucket histogram ----------------
__global__ __launch_bounds__(256) void k_hist(const int* __restrict__ dst,
                                              int* __restrict__ histM) {
  __shared__ int hist[NBUK];
  int b = blockIdx.x, t = threadIdx.x;
  for (int i = t; i < NBUK; i += 256) hist[i] = 0;
  __syncthreads();
  int e0 = b * SEGE, e1 = min(e0 + SEGE, NE);
  for (int e = e0 + t; e < e1; e += 256) atomicAdd(&hist[dst[e] >> 7], 1);
  __syncthreads();
  for (int i = t; i < NBUK; i += 256) histM[b * NBUKP + i] = hist[i];
}

// ---------------- pass 2: per-bucket prefix over segments (parallel) --------
__global__ __launch_bounds__(256) void k_colscan(const int* __restrict__ histM,
                                                 int* __restrict__ segbase,
                                                 int* __restrict__ btot) {
  __shared__ int lds[256];
  int b = blockIdx.x, t = threadIdx.x;
  int s0 = t * 2, s1 = t * 2 + 1;
  int v0 = (s0 < NSEG) ? histM[s0 * NBUKP + b] : 0;
  int v1 = (s1 < NSEG) ? histM[s1 * NBUKP + b] : 0;
  int pair = v0 + v1;
  lds[t] = pair;
  __syncthreads();
  int mine = pair;
  for (int off = 1; off < 256; off <<= 1) {
    int add = (t >= off) ? lds[t - off] : 0;
    __syncthreads();
    lds[t] += add;
    __syncthreads();
  }
  int run = lds[t] - mine;
  if (s0 < NSEG) segbase[s0 * NBUKP + b] = run;
  if (s1 < NSEG) segbase[s1 * NBUKP + b] = run + v0;
  if (t == 255) btot[b] = lds[255];
}

// ---------------- pass 3: scatter into buckets, LDS cursors, packed u32 ------
__global__ __launch_bounds__(256) void k_scatter2(const int* __restrict__ src,
                                                  const int* __restrict__ dst,
                                                  const int* __restrict__ segbase,
                                                  unsigned int* __restrict__ buck) {
  __shared__ int base[NBUK];
  int b = blockIdx.x, t = threadIdx.x;
  for (int i = t; i < NBUK; i += 256) base[i] = segbase[b * NBUKP + i];
  __syncthreads();
  int e0 = b * SEGE, e1 = min(e0 + SEGE, NE);
  for (int e = e0 + t; e < e1; e += 256) {
    int s = src[e], d = dst[e];
    int bk = d >> 7;
    int slot = atomicAdd(&base[bk], 1);
    buck[(size_t)bk * BCAP + slot] = ((unsigned int)(d & 127) << 17) | (unsigned int)s;
  }
}

// ---------------- bucket-base: exclusive scan of btot (1 block) -------------
__global__ __launch_bounds__(256) void k_btotscan(const int* __restrict__ btot,
                                                  int* __restrict__ bbase) {
  __shared__ int lds[256];
  int t = threadIdx.x;
  int v[4];
  int s = 0;
#pragma unroll
  for (int i = 0; i < 4; ++i) {
    int idx = t * 4 + i;
    v[i] = (idx < NBUK) ? btot[idx] : 0;
    s += v[i];
  }
  lds[t] = s;
  __syncthreads();
  int mine = s;
  for (int off = 1; off < 256; off <<= 1) {
    int add = (t >= off) ? lds[t - off] : 0;
    __syncthreads();
    lds[t] += add;
    __syncthreads();
  }
  int run = lds[t] - mine;
#pragma unroll
  for (int i = 0; i < 4; ++i) {
    int idx = t * 4 + i;
    if (idx < NBUK) {
      bbase[idx] = run;
      run += v[i];
    }
  }
}

// ---------------- finalize: per-bucket count + scan + place (one pass) ------
__global__ __launch_bounds__(256) void k_finalize(const int* __restrict__ btot,
                                                  const int* __restrict__ bbase,
                                                  const unsigned int* __restrict__ buck,
                                                  int* __restrict__ row_start,
                                                  float* __restrict__ dinv,
                                                  int* __restrict__ csr_src) {
  __shared__ unsigned int ebuf[BCAP];  // 12 KB
  __shared__ int cnt[128];
  __shared__ int xoff[128];
  int b = blockIdx.x, t = threadIdx.x;
  int nb = btot[b];
  int base = bbase[b];
  const unsigned int* bp = buck + (size_t)b * BCAP;
  for (int i = t; i < nb; i += 256) ebuf[i] = bp[i];
  if (t < 128) cnt[t] = 0;
  __syncthreads();
  for (int i = t; i < nb; i += 256) atomicAdd(&cnt[ebuf[i] >> 17], 1);
  __syncthreads();
  if (t < 128) xoff[t] = cnt[t];
  __syncthreads();
  for (int off = 1; off < 128; off <<= 1) {
    int add = 0;
    if (t < 128 && t >= off) add = xoff[t - off];
    __syncthreads();
    if (t < 128) xoff[t] += add;
    __syncthreads();
  }
  if (t < 128) {
    int node = b * 128 + t;
    int ex = xoff[t] - cnt[t];
    if (node < NN) {
      row_start[node] = base + ex;
      dinv[node] = rsqrtf((float)cnt[t] + 1.0f);
    }
    xoff[t] = ex;   // exclusive offset for placement
    cnt[t] = 0;     // reuse as cursor
  }
  if (b == 0 && t == 0) row_start[NN] = NE;
  __syncthreads();
  for (int i = t; i < nb; i += 256) {
    unsigned int p = ebuf[i];
    int dl = (int)(p >> 17);
    int l = atomicAdd(&cnt[dl], 1);
    csr_src[base + xoff[dl] + l] = (int)(p & 0x1FFFFu);
  }
}

// ---------------- fused setup: W1/W2 -> fragment-ordered bf16 hi/lo + BN ----
__global__ __launch_bounds__(256) void k_prep(const float* __restrict__ W1,
                                              const float* __restrict__ W2,
                                              unsigned short* __restrict__ w1hi,
                                              unsigned short* __restrict__ w1lo,
                                              unsigned short* __restrict__ w2hi,
                                              unsigned short* __restrict__ w2lo,
                                              const float* __restrict__ b1, const float* __restrict__ g1,
                                              const float* __restrict__ be1, const float* __restrict__ m1,
                                              const float* __restrict__ v1,
                                              const float* __restrict__ b2, const float* __restrict__ g2,
                                              const float* __restrict__ be2, const float* __restrict__ m2,
                                              const float* __restrict__ v2,
                                              float* __restrict__ sc1, float* __restrict__ sh1,
                                              float* __restrict__ sc2, float* __restrict__ sh2) {
  int b = blockIdx.x, t = threadIdx.x;
  if (b < 128) {
    const float* W = (b < 64) ? W1 : W2;
    unsigned short* whi = (b < 64) ? w1hi : w2hi;
    unsigned short* wlo = (b < 64) ? w1lo : w2lo;
    int i = ((b & 63) * 256 + t);
    int k = i >> 7, n = i & 127;
    float w = W[i];
    unsigned short h = f2bf(w);
    unsigned short l = f2bf(w - bf2f(h));
    int idx = ((((k >> 5) * 8) + (n >> 4)) * 64 + ((k >> 3) & 3) * 16 + (n & 15)) * 8 + (k & 7);
    whi[idx] = h;
    wlo[idx] = l;
  } else {
    if (t < FD) {
      float s = g1[t] * rsqrtf(v1[t] + BN_EPS);
      sc1[t] = s;
      sh1[t] = (b1[t] - m1[t]) * s + be1[t];
    } else if (t < 2 * FD) {
      int f = t - FD;
      float s = g2[f] * rsqrtf(v2[f] + BN_EPS);
      sc2[f] = s;
      sh2[f] = (b2[f] - m2[f]) * s + be2[f];
    }
  }
}

// ---------------- LDS-free MFMA GEMM 128x128 -> pre-scaled bf16 rows --------
__global__ __launch_bounds__(256) void k_gemm128_mfma(const float* __restrict__ X,
                                                      const unsigned short* __restrict__ whi,
                                                      const unsigned short* __restrict__ wlo,
                                                      const float* __restrict__ dinv,
                                                      unsigned short* __restrict__ Hbs,
                                                      int nrows) {
  int tid = threadIdx.x;
  int lane = tid & 63, wv = tid >> 6;
  int lg = lane >> 4, li = lane & 15;
  int wr0 = blockIdx.x * 64 + wv * 16;
  int row = wr0 + li;
  bool ok = row < nrows;

  short8 ahi[4], alo[4];
#pragma unroll
  for (int ks = 0; ks < 4; ++ks) {
    if (ok) {
      const float* xp = X + (unsigned)(row * FD + ks * 32 + lg * 8);
      float4 v0 = *(const float4*)xp;
      float4 v1 = *(const float4*)(xp + 4);
      float f[8] = {v0.x, v0.y, v0.z, v0.w, v1.x, v1.y, v1.z, v1.w};
      unsigned int hp[4], lp[4];
#pragma unroll
      for (int j = 0; j < 4; ++j) {
        float a = f[2 * j], c = f[2 * j + 1];
        hp[j] = cvt_pk_bf16(a, c);
        float ra = a - blo(hp[j]);
        float rc = c - bhi(hp[j]);
        lp[j] = cvt_pk_bf16(ra, rc);
      }
      uint4 hv = {hp[0], hp[1], hp[2], hp[3]};
      uint4 lv = {lp[0], lp[1], lp[2], lp[3]};
      ahi[ks] = __builtin_bit_cast(short8, hv);
      alo[ks] = __builtin_bit_cast(short8, lv);
    } else {
#pragma unroll
      for (int j = 0; j < 8; ++j) { ahi[ks][j] = 0; alo[ks][j] = 0; }
    }
  }

  int rb = wr0 + lg * 4;
  float dvr[4];
#pragma unroll
  for (int r = 0; r < 4; ++r) dvr[r] = (rb + r < nrows) ? dinv[rb + r] : 0.f;

#pragma unroll
  for (int nt = 0; nt < 8; ++nt) {
    f32x4 acc = {0.f, 0.f, 0.f, 0.f};
#pragma unroll
    for (int ks = 0; ks < 4; ++ks) {
      unsigned int bidx = (unsigned)(((ks * 8 + nt) * 64 + lane) * 8);
      short8 bh = *(const short8*)&whi[bidx];
      short8 bl = *(const short8*)&wlo[bidx];
      acc = __builtin_amdgcn_mfma_f32_16x16x32_bf16(ahi[ks], bh, acc, 0, 0, 0);
      acc = __builtin_amdgcn_mfma_f32_16x16x32_bf16(alo[ks], bh, acc, 0, 0, 0);
      acc = __builtin_amdgcn_mfma_f32_16x16x32_bf16(ahi[ks], bl, acc, 0, 0, 0);
    }
    // C/D: col = lane&15, row = (lane>>4)*4 + reg   [m89-verified]
    int col = nt * 16 + li;
#pragma unroll
    for (int r = 0; r < 4; ++r) {
      if (rb + r < nrows)
        Hbs[(unsigned)((rb + r) * FD + col)] = f2bf(acc[r] * dvr[r]);
    }
  }
}

// ---------------- node-parallel gather over pre-scaled bf16 rows ------------
// node wave-uniform (readfirstlane); 32-bit offsets -> saddr-form loads.
template <bool BN>
__global__ __launch_bounds__(256) void k_gather128(const int* __restrict__ row_start,
                                                   const int* __restrict__ csr_src,
                                                   const float* __restrict__ dinv,
                                                   const unsigned short* __restrict__ Hbs,
                                                   const float* __restrict__ sc,
                                                   const float* __restrict__ sh,
                                                   float* __restrict__ AGG) {
  int node = blockIdx.x * 4 + (threadIdx.x >> 6);   // NN % 4 == 0: always valid
  node = __builtin_amdgcn_readfirstlane(node);
  int lane = threadIdx.x & 63;
  const unsigned int* Hc = (const unsigned int*)Hbs;  // [N][64] packed bf16x2
  int beg = row_start[node], end = row_start[node + 1];
  float px0 = 0.f, px1 = 0.f, px2 = 0.f, px3 = 0.f;
  float py0 = 0.f, py1 = 0.f, py2 = 0.f, py3 = 0.f;
  {
    unsigned int us = Hc[(unsigned)(node * 64) + lane];   // self row (pre-scaled)
    px0 = blo(us); py0 = bhi(us);
  }
  int e = beg;
  for (; e + 3 < end; e += 4) {
    unsigned int u0 = Hc[((unsigned)csr_src[e + 0] << 6) + lane];
    unsigned int u1 = Hc[((unsigned)csr_src[e + 1] << 6) + lane];
    unsigned int u2 = Hc[((unsigned)csr_src[e + 2] << 6) + lane];
    unsigned int u3 = Hc[((unsigned)csr_src[e + 3] << 6) + lane];
    px0 += blo(u0); py0 += bhi(u0);
    px1 += blo(u1); py1 += bhi(u1);
    px2 += blo(u2); py2 += bhi(u2);
    px3 += blo(u3); py3 += bhi(u3);
  }
  for (; e < end; ++e) {
    unsigned int u0 = Hc[((unsigned)csr_src[e] << 6) + lane];
    px0 += blo(u0); py0 += bhi(u0);
  }
  float dv = dinv[node];
  float accx = ((px0 + px1) + (px2 + px3)) * dv;
  float accy = ((py0 + py1) + (py2 + py3)) * dv;
  if (BN) {
    float scx = sc[lane * 2], scy = sc[lane * 2 + 1];
    float shx = sh[lane * 2], shy = sh[lane * 2 + 1];
    accx = fmaxf(fmaf(accx, scx, shx), 0.f);
    accy = fmaxf(fmaf(accy, scy, shy), 0.f);
  }
  float2 o; o.x = accx; o.y = accy;
  ((float2*)AGG)[(unsigned)(node * 64) + lane] = o;
}

// ---------------- output GEMM 128->10 ----------------
__global__ __launch_bounds__(256) void k_gemm_out(const float* __restrict__ X,
                                                  const float* __restrict__ W3,
                                                  float* __restrict__ H3, int nrows) {
  __shared__ float ws[FD * 16];
  int tid = threadIdx.x;
  for (int i = tid; i < FD * 16; i += 256) {
    int k = i >> 4, c = i & 15;
    ws[i] = (c < CO) ? W3[k * CO + c] : 0.f;
  }
  __syncthreads();
  int grp = tid >> 4;
  int c = tid & 15;
  int r = blockIdx.x * 16 + grp;
  if (r >= nrows) return;
  const float* x = X + (unsigned)(r * FD);
  float acc = 0.f;
#pragma unroll
  for (int k = 0; k < FD; k += 4) {
    float4 xv = *(const float4*)&x[k];
    acc += xv.x * ws[(k + 0) * 16 + c];
    acc += xv.y * ws[(k + 1) * 16 + c];
    acc += xv.z * ws[(k + 2) * 16 + c];
    acc += xv.w * ws[(k + 3) * 16 + c];
  }
  if (c < CO) H3[(unsigned)(r * CO + c)] = acc;
}

// ---------------- gather 10 feat, fused self-loop + bias, writes out --------
__global__ __launch_bounds__(256) void k_gather10(const int* __restrict__ row_start,
                                                  const int* __restrict__ csr_src,
                                                  const float* __restrict__ dinv,
                                                  const float* __restrict__ H3,
                                                  const float* __restrict__ b3,
                                                  float* __restrict__ out) {
  int node = blockIdx.x * 16 + (threadIdx.x >> 4);
  if (node >= NN) return;
  int c = threadIdx.x & 15;
  int beg = row_start[node], end = row_start[node + 1];
  float dv = dinv[node];
  float acc = 0.f;
  if (c < CO) acc = H3[(unsigned)(node * CO + c)] * (dv * dv);
  for (int e = beg; e < end; ++e) {
    int s = csr_src[e];
    float cf = dinv[s] * dv;
    if (c < CO) acc = fmaf(H3[(unsigned)(s * CO + c)], cf, acc);
  }
  if (c < CO) out[(unsigned)(node * CO + c)] = acc + b3[c];
}

// ---------------- launch ----------------
extern "C" void kernel_launch(void* const* d_in, const int* in_sizes, int n_in,
                              void* d_out, int out_size, void* d_ws, size_t ws_size,
                              hipStream_t stream) {
  const float* x = (const float*)d_in[0];
  const int* src = (const int*)d_in[1];
  const int* dst = (const int*)d_in[2];
  const float* W1 = (const float*)d_in[3];
  const float* b1 = (const float*)d_in[4];
  const float* g1 = (const float*)d_in[5];
  const float* be1 = (const float*)d_in[6];
  const float* m1 = (const float*)d_in[7];
  const float* v1 = (const float*)d_in[8];
  const float* W2 = (const float*)d_in[9];
  const float* b2 = (const float*)d_in[10];
  const float* g2 = (const float*)d_in[11];
  const float* be2 = (const float*)d_in[12];
  const float* m2 = (const float*)d_in[13];
  const float* v2 = (const float*)d_in[14];
  const float* W3 = (const float*)d_in[15];
  const float* b3 = (const float*)d_in[16];
  float* out = (float*)d_out;

  char* wsb = (char*)d_ws;
  int* row_start = (int*)wsb;                 wsb += (NN + 1) * 4;
  int* histM = (int*)wsb;                     wsb += (size_t)NSEG * NBUKP * 4;
  int* segbase = (int*)wsb;                   wsb += (size_t)NSEG * NBUKP * 4;
  int* btot = (int*)wsb;                      wsb += NBUKP * 4;
  int* bbase = (int*)wsb;                     wsb += NBUKP * 4;
  float* dinv = (float*)wsb;                  wsb += NN * 4;
  float* sc1 = (float*)wsb;                   wsb += FD * 4;
  float* sh1 = (float*)wsb;                   wsb += FD * 4;
  float* sc2 = (float*)wsb;                   wsb += FD * 4;
  float* sh2 = (float*)wsb;                   wsb += FD * 4;
  unsigned short* w1hi = (unsigned short*)wsb; wsb += FD * FD * 2;
  unsigned short* w1lo = (unsigned short*)wsb; wsb += FD * FD * 2;
  unsigned short* w2hi = (unsigned short*)wsb; wsb += FD * FD * 2;
  unsigned short* w2lo = (unsigned short*)wsb; wsb += FD * FD * 2;
  int* csr_src = (int*)wsb;                   wsb += (size_t)NE * 4;
  unsigned int* buck = (unsigned int*)wsb;    wsb += (size_t)NBUK * BCAP * 4;
  float* AGG = (float*)wsb;                   wsb += (size_t)NN * FD * 4;   // [N][128] f32
  unsigned short* Hbs = (unsigned short*)wsb; wsb += (size_t)NN * FD * 2;   // [N][128] bf16
  float* H3 = (float*)Hbs;  // layer-3 reuse (Hbs dead after layer-2 gather)

  k_hist<<<NSEG, 256, 0, stream>>>(dst, histM);
  k_colscan<<<NBUK, 256, 0, stream>>>(histM, segbase, btot);
  k_scatter2<<<NSEG, 256, 0, stream>>>(src, dst, segbase, buck);
  k_btotscan<<<1, 256, 0, stream>>>(btot, bbase);
  k_finalize<<<NBUK, 256, 0, stream>>>(btot, bbase, buck, row_start, dinv, csr_src);
  k_prep<<<129, 256, 0, stream>>>(W1, W2, w1hi, w1lo, w2hi, w2lo,
                                  b1, g1, be1, m1, v1, b2, g2, be2, m2, v2,
                                  sc1, sh1, sc2, sh2);

  int gemm_blocks = (NN + 63) / 64;
  int gat_blocks = (NN + 3) / 4;

  // layer 1
  k_gemm128_mfma<<<gemm_blocks, 256, 0, stream>>>(x, w1hi, w1lo, dinv, Hbs, NN);
  k_gather128<true><<<gat_blocks, 256, 0, stream>>>(row_start, csr_src, dinv,
                                                    Hbs, sc1, sh1, AGG);
  // layer 2
  k_gemm128_mfma<<<gemm_blocks, 256, 0, stream>>>(AGG, w2hi, w2lo, dinv, Hbs, NN);
  k_gather128<true><<<gat_blocks, 256, 0, stream>>>(row_start, csr_src, dinv,
                                                    Hbs, sc2, sh2, AGG);
  // layer 3
  k_gemm_out<<<(NN + 15) / 16, 256, 0, stream>>>(AGG, W3, H3, NN);
  k_gather10<<<(NN + 15) / 16, 256, 0, stream>>>(row_start, csr_src, dinv,
                                                 H3, b3, out);
}

// Round 13
// 313.864 us; speedup vs baseline: 1.4310x; 1.1375x over previous
//
#include <hip/hip_runtime.h>

#define NN 100000
#define NE 1600000
#define FD 128
#define CO 10
#define BN_EPS 1e-5f
#define NBUK 782                               // buckets of 128 nodes
#define NBUKP 784
#define BCAP 3072
#define SEGE 4096
#define NSEG 391

typedef __attribute__((ext_vector_type(8))) short short8;
typedef __attribute__((ext_vector_type(4))) float f32x4;

__device__ __forceinline__ unsigned short f2bf(float f) {
  unsigned int u = __builtin_bit_cast(unsigned int, f);
  u = (u + 0x7FFFu + ((u >> 16) & 1u)) >> 16;
  return (unsigned short)u;
}
__device__ __forceinline__ float bf2f(unsigned short h) {
  unsigned int u = ((unsigned int)h) << 16;
  return __builtin_bit_cast(float, u);
}
__device__ __forceinline__ float blo(unsigned int u) {
  return __builtin_bit_cast(float, u << 16);
}
__device__ __forceinline__ float bhi(unsigned int u) {
  return __builtin_bit_cast(float, u & 0xFFFF0000u);
}
__device__ __forceinline__ unsigned int cvt_pk_bf16(float a, float b) {
  unsigned int r;
  asm("v_cvt_pk_bf16_f32 %0, %1, %2" : "=v"(r) : "v"(a), "v"(b));
  return r;
}

// ---------------- fused: per-segment histogram + W-convert + BN constants ----
// blocks 0..390: hist; 391..518: W1/W2 fragment-order bf16 hi/lo; 519: BN.
__global__ __launch_bounds__(256) void k_hist_prep(
    const int* __restrict__ dst, int* __restrict__ histM,
    const float* __restrict__ W1, const float* __restrict__ W2,
    unsigned short* __restrict__ w1hi, unsigned short* __restrict__ w1lo,
    unsigned short* __restrict__ w2hi, unsigned short* __restrict__ w2lo,
    const float* __restrict__ b1, const float* __restrict__ g1,
    const float* __restrict__ be1, const float* __restrict__ m1,
    const float* __restrict__ v1,
    const float* __restrict__ b2, const float* __restrict__ g2,
    const float* __restrict__ be2, const float* __restrict__ m2,
    const float* __restrict__ v2,
    float* __restrict__ sc1, float* __restrict__ sh1,
    float* __restrict__ sc2, float* __restrict__ sh2) {
  __shared__ int hist[NBUK];
  int b = blockIdx.x, t = threadIdx.x;
  if (b < NSEG) {
    for (int i = t; i < NBUK; i += 256) hist[i] = 0;
    __syncthreads();
    int e0 = b * SEGE, e1 = min(e0 + SEGE, NE);
    for (int e = e0 + t; e < e1; e += 256) atomicAdd(&hist[dst[e] >> 7], 1);
    __syncthreads();
    for (int i = t; i < NBUK; i += 256) histM[b * NBUKP + i] = hist[i];
  } else if (b < NSEG + 128) {
    int bb = b - NSEG;
    const float* W = (bb < 64) ? W1 : W2;
    unsigned short* whi = (bb < 64) ? w1hi : w2hi;
    unsigned short* wlo = (bb < 64) ? w1lo : w2lo;
    int i = (bb & 63) * 256 + t;
    int k = i >> 7, n = i & 127;
    float w = W[i];
    unsigned short h = f2bf(w);
    unsigned short l = f2bf(w - bf2f(h));
    int idx = ((((k >> 5) * 8) + (n >> 4)) * 64 + ((k >> 3) & 3) * 16 + (n & 15)) * 8 + (k & 7);
    whi[idx] = h;
    wlo[idx] = l;
  } else {
    if (t < FD) {
      float s = g1[t] * rsqrtf(v1[t] + BN_EPS);
      sc1[t] = s;
      sh1[t] = (b1[t] - m1[t]) * s + be1[t];
    } else if (t < 2 * FD) {
      int f = t - FD;
      float s = g2[f] * rsqrtf(v2[f] + BN_EPS);
      sc2[f] = s;
      sh2[f] = (b2[f] - m2[f]) * s + be2[f];
    }
  }
}

// ---------------- per-bucket prefix over segments (parallel) ----------------
__global__ __launch_bounds__(256) void k_colscan(const int* __restrict__ histM,
                                                 int* __restrict__ segbase,
                                                 int* __restrict__ btot) {
  __shared__ int lds[256];
  int b = blockIdx.x, t = threadIdx.x;
  int s0 = t * 2, s1 = t * 2 + 1;
  int v0 = (s0 < NSEG) ? histM[s0 * NBUKP + b] : 0;
  int v1 = (s1 < NSEG) ? histM[s1 * NBUKP + b] : 0;
  int pair = v0 + v1;
  lds[t] = pair;
  __syncthreads();
  int mine = pair;
  for (int off = 1; off < 256; off <<= 1) {
    int add = (t >= off) ? lds[t - off] : 0;
    __syncthreads();
    lds[t] += add;
    __syncthreads();
  }
  int run = lds[t] - mine;
  if (s0 < NSEG) segbase[s0 * NBUKP + b] = run;
  if (s1 < NSEG) segbase[s1 * NBUKP + b] = run + v0;
  if (t == 255) btot[b] = lds[255];
}

// ---------------- scatter into buckets, LDS cursors, packed u32 -------------
__global__ __launch_bounds__(256) void k_scatter2(const int* __restrict__ src,
                                                  const int* __restrict__ dst,
                                                  const int* __restrict__ segbase,
                                                  unsigned int* __restrict__ buck) {
  __shared__ int base[NBUK];
  int b = blockIdx.x, t = threadIdx.x;
  for (int i = t; i < NBUK; i += 256) base[i] = segbase[b * NBUKP + i];
  __syncthreads();
  int e0 = b * SEGE, e1 = min(e0 + SEGE, NE);
  for (int e = e0 + t; e < e1; e += 256) {
    int s = src[e], d = dst[e];
    int bk = d >> 7;
    int slot = atomicAdd(&base[bk], 1);
    buck[(size_t)bk * BCAP + slot] = ((unsigned int)(d & 127) << 17) | (unsigned int)s;
  }
}

// ---------------- finalize: count + local scan + nrange + place -------------
// Padded CSR: bucket b's edges live at csr_src[b*BCAP ...]. No global scan.
__global__ __launch_bounds__(256) void k_finalize(const int* __restrict__ btot,
                                                  const unsigned int* __restrict__ buck,
                                                  uint4* __restrict__ nrange,
                                                  int* __restrict__ csr_src) {
  __shared__ unsigned int ebuf[BCAP];  // 12 KB
  __shared__ int cnt[128];
  __shared__ int xoff[128];
  int b = blockIdx.x, t = threadIdx.x;
  int nb = btot[b];
  const unsigned int* bp = buck + (size_t)b * BCAP;
  for (int i = t; i < nb; i += 256) ebuf[i] = bp[i];
  if (t < 128) cnt[t] = 0;
  __syncthreads();
  for (int i = t; i < nb; i += 256) atomicAdd(&cnt[ebuf[i] >> 17], 1);
  __syncthreads();
  if (t < 128) xoff[t] = cnt[t];
  __syncthreads();
  for (int off = 1; off < 128; off <<= 1) {
    int add = 0;
    if (t < 128 && t >= off) add = xoff[t - off];
    __syncthreads();
    if (t < 128) xoff[t] += add;
    __syncthreads();
  }
  if (t < 128) {
    int node = b * 128 + t;
    int ex = xoff[t] - cnt[t];
    if (node < NN) {
      uint4 nr;
      nr.x = (unsigned)(b * BCAP + ex);
      nr.y = (unsigned)cnt[t];
      nr.z = __builtin_bit_cast(unsigned int, rsqrtf((float)cnt[t] + 1.0f));
      nr.w = 0;
      nrange[node] = nr;
    }
    xoff[t] = ex;
    cnt[t] = 0;
  }
  __syncthreads();
  int base = b * BCAP;
  for (int i = t; i < nb; i += 256) {
    unsigned int p = ebuf[i];
    int dl = (int)(p >> 17);
    int l = atomicAdd(&cnt[dl], 1);
    csr_src[base + xoff[dl] + l] = (int)(p & 0x1FFFFu);
  }
}

// ---------------- LDS-free MFMA GEMM 128x128 -> pre-scaled bf16 rows --------
__global__ __launch_bounds__(256) void k_gemm128_mfma(const float* __restrict__ X,
                                                      const unsigned short* __restrict__ whi,
                                                      const unsigned short* __restrict__ wlo,
                                                      const uint4* __restrict__ nrange,
                                                      unsigned short* __restrict__ Hbs,
                                                      int nrows) {
  int tid = threadIdx.x;
  int lane = tid & 63, wv = tid >> 6;
  int lg = lane >> 4, li = lane & 15;
  int wr0 = blockIdx.x * 64 + wv * 16;
  int row = wr0 + li;
  bool ok = row < nrows;

  short8 ahi[4], alo[4];
#pragma unroll
  for (int ks = 0; ks < 4; ++ks) {
    if (ok) {
      const float* xp = X + (unsigned)(row * FD + ks * 32 + lg * 8);
      float4 v0 = *(const float4*)xp;
      float4 v1 = *(const float4*)(xp + 4);
      float f[8] = {v0.x, v0.y, v0.z, v0.w, v1.x, v1.y, v1.z, v1.w};
      unsigned int hp[4], lp[4];
#pragma unroll
      for (int j = 0; j < 4; ++j) {
        float a = f[2 * j], c = f[2 * j + 1];
        hp[j] = cvt_pk_bf16(a, c);
        float ra = a - blo(hp[j]);
        float rc = c - bhi(hp[j]);
        lp[j] = cvt_pk_bf16(ra, rc);
      }
      uint4 hv = {hp[0], hp[1], hp[2], hp[3]};
      uint4 lv = {lp[0], lp[1], lp[2], lp[3]};
      ahi[ks] = __builtin_bit_cast(short8, hv);
      alo[ks] = __builtin_bit_cast(short8, lv);
    } else {
#pragma unroll
      for (int j = 0; j < 8; ++j) { ahi[ks][j] = 0; alo[ks][j] = 0; }
    }
  }

  int rb = wr0 + lg * 4;
  float dvr[4];
#pragma unroll
  for (int r = 0; r < 4; ++r)
    dvr[r] = (rb + r < nrows) ? __builtin_bit_cast(float, nrange[rb + r].z) : 0.f;

#pragma unroll
  for (int nt = 0; nt < 8; ++nt) {
    f32x4 acc = {0.f, 0.f, 0.f, 0.f};
#pragma unroll
    for (int ks = 0; ks < 4; ++ks) {
      unsigned int bidx = (unsigned)(((ks * 8 + nt) * 64 + lane) * 8);
      short8 bh = *(const short8*)&whi[bidx];
      short8 bl = *(const short8*)&wlo[bidx];
      acc = __builtin_amdgcn_mfma_f32_16x16x32_bf16(ahi[ks], bh, acc, 0, 0, 0);
      acc = __builtin_amdgcn_mfma_f32_16x16x32_bf16(alo[ks], bh, acc, 0, 0, 0);
      acc = __builtin_amdgcn_mfma_f32_16x16x32_bf16(ahi[ks], bl, acc, 0, 0, 0);
    }
    // C/D: col = lane&15, row = (lane>>4)*4 + reg   [m89-verified]
    int col = nt * 16 + li;
#pragma unroll
    for (int r = 0; r < 4; ++r) {
      if (rb + r < nrows)
        Hbs[(unsigned)((rb + r) * FD + col)] = f2bf(acc[r] * dvr[r]);
    }
  }
}

// ---------------- layer-1 gather: bf16 rows -> BN+ReLU -> f32 AGG -----------
__global__ __launch_bounds__(256) void k_gather128(const uint4* __restrict__ nrange,
                                                   const int* __restrict__ csr_src,
                                                   const unsigned short* __restrict__ Hbs,
                                                   const float* __restrict__ sc,
                                                   const float* __restrict__ sh,
                                                   float* __restrict__ AGG) {
  int node = blockIdx.x * 4 + (threadIdx.x >> 6);   // NN % 4 == 0
  node = __builtin_amdgcn_readfirstlane(node);
  int lane = threadIdx.x & 63;
  const unsigned int* Hc = (const unsigned int*)Hbs;
  uint4 nr = nrange[node];
  int beg = (int)nr.x, end = (int)(nr.x + nr.y);
  float dv = __builtin_bit_cast(float, nr.z);
  float px0, px1 = 0.f, px2 = 0.f, px3 = 0.f;
  float py0, py1 = 0.f, py2 = 0.f, py3 = 0.f;
  {
    unsigned int us = Hc[(unsigned)(node * 64) + lane];
    px0 = blo(us); py0 = bhi(us);
  }
  int e = beg;
  for (; e + 3 < end; e += 4) {
    unsigned int u0 = Hc[((unsigned)csr_src[e + 0] << 6) + lane];
    unsigned int u1 = Hc[((unsigned)csr_src[e + 1] << 6) + lane];
    unsigned int u2 = Hc[((unsigned)csr_src[e + 2] << 6) + lane];
    unsigned int u3 = Hc[((unsigned)csr_src[e + 3] << 6) + lane];
    px0 += blo(u0); py0 += bhi(u0);
    px1 += blo(u1); py1 += bhi(u1);
    px2 += blo(u2); py2 += bhi(u2);
    px3 += blo(u3); py3 += bhi(u3);
  }
  for (; e < end; ++e) {
    unsigned int u0 = Hc[((unsigned)csr_src[e] << 6) + lane];
    px0 += blo(u0); py0 += bhi(u0);
  }
  float accx = ((px0 + px1) + (px2 + px3)) * dv;
  float accy = ((py0 + py1) + (py2 + py3)) * dv;
  float scx = sc[lane * 2], scy = sc[lane * 2 + 1];
  float shx = sh[lane * 2], shy = sh[lane * 2 + 1];
  accx = fmaxf(fmaf(accx, scx, shx), 0.f);
  accy = fmaxf(fmaf(accy, scy, shy), 0.f);
  float2 o; o.x = accx; o.y = accy;
  ((float2*)AGG)[(unsigned)(node * 64) + lane] = o;
}

// ---------------- layer-2 gather + BN + fused W3 GEMM -> pre-scaled H3s -----
__global__ __launch_bounds__(256) void k_gather128_out(const uint4* __restrict__ nrange,
                                                       const int* __restrict__ csr_src,
                                                       const unsigned short* __restrict__ Hbs,
                                                       const float* __restrict__ sc,
                                                       const float* __restrict__ sh,
                                                       const float* __restrict__ W3,
                                                       float* __restrict__ H3s) {
  int node = blockIdx.x * 4 + (threadIdx.x >> 6);
  node = __builtin_amdgcn_readfirstlane(node);
  int lane = threadIdx.x & 63;
  // per-lane W3 rows (2 rows x 10) in registers
  float w3r[20];
  {
    const float* wp = W3 + lane * 2 * CO;
#pragma unroll
    for (int j = 0; j < 20; ++j) w3r[j] = wp[j];
  }
  const unsigned int* Hc = (const unsigned int*)Hbs;
  uint4 nr = nrange[node];
  int beg = (int)nr.x, end = (int)(nr.x + nr.y);
  float dv = __builtin_bit_cast(float, nr.z);
  float px0, px1 = 0.f, px2 = 0.f, px3 = 0.f;
  float py0, py1 = 0.f, py2 = 0.f, py3 = 0.f;
  {
    unsigned int us = Hc[(unsigned)(node * 64) + lane];
    px0 = blo(us); py0 = bhi(us);
  }
  int e = beg;
  for (; e + 3 < end; e += 4) {
    unsigned int u0 = Hc[((unsigned)csr_src[e + 0] << 6) + lane];
    unsigned int u1 = Hc[((unsigned)csr_src[e + 1] << 6) + lane];
    unsigned int u2 = Hc[((unsigned)csr_src[e + 2] << 6) + lane];
    unsigned int u3 = Hc[((unsigned)csr_src[e + 3] << 6) + lane];
    px0 += blo(u0); py0 += bhi(u0);
    px1 += blo(u1); py1 += bhi(u1);
    px2 += blo(u2); py2 += bhi(u2);
    px3 += blo(u3); py3 += bhi(u3);
  }
  for (; e < end; ++e) {
    unsigned int u0 = Hc[((unsigned)csr_src[e] << 6) + lane];
    px0 += blo(u0); py0 += bhi(u0);
  }
  float accx = ((px0 + px1) + (px2 + px3)) * dv;
  float accy = ((py0 + py1) + (py2 + py3)) * dv;
  float scx = sc[lane * 2], scy = sc[lane * 2 + 1];
  float shx = sh[lane * 2], shy = sh[lane * 2 + 1];
  accx = fmaxf(fmaf(accx, scx, shx), 0.f);
  accy = fmaxf(fmaf(accy, scy, shy), 0.f);
  // fused 128->10 GEMM: per-lane partials, butterfly sum across 64 lanes
  float p[10];
#pragma unroll
  for (int c = 0; c < CO; ++c) p[c] = fmaf(accx, w3r[c], accy * w3r[10 + c]);
#pragma unroll
  for (int off = 32; off >= 1; off >>= 1) {
#pragma unroll
    for (int c = 0; c < CO; ++c) p[c] += __shfl_xor(p[c], off);
  }
  // pre-scale by dinv[node]; lanes 0..9 write
#pragma unroll
  for (int c = 0; c < CO; ++c)
    if (lane == c) H3s[(unsigned)(node * CO + c)] = p[c] * dv;
}

// ---------------- gather 10 feat over pre-scaled H3s, + bias -> out ---------
__global__ __launch_bounds__(256) void k_gather10(const uint4* __restrict__ nrange,
                                                  const int* __restrict__ csr_src,
                                                  const float* __restrict__ H3s,
                                                  const float* __restrict__ b3,
                                                  float* __restrict__ out) {
  int node = blockIdx.x * 16 + (threadIdx.x >> 4);
  if (node >= NN) return;
  int c = threadIdx.x & 15;
  uint4 nr = nrange[node];
  int beg = (int)nr.x, end = (int)(nr.x + nr.y);
  float dv = __builtin_bit_cast(float, nr.z);
  float acc = 0.f;
  if (c < CO) acc = H3s[(unsigned)(node * CO + c)];   // self (pre-scaled)
  for (int e = beg; e < end; ++e) {
    int s = csr_src[e];
    if (c < CO) acc += H3s[(unsigned)(s * CO + c)];
  }
  if (c < CO) out[(unsigned)(node * CO + c)] = fmaf(acc, dv, b3[c]);
}

// ---------------- launch ----------------
extern "C" void kernel_launch(void* const* d_in, const int* in_sizes, int n_in,
                              void* d_out, int out_size, void* d_ws, size_t ws_size,
                              hipStream_t stream) {
  const float* x = (const float*)d_in[0];
  const int* src = (const int*)d_in[1];
  const int* dst = (const int*)d_in[2];
  const float* W1 = (const float*)d_in[3];
  const float* b1 = (const float*)d_in[4];
  const float* g1 = (const float*)d_in[5];
  const float* be1 = (const float*)d_in[6];
  const float* m1 = (const float*)d_in[7];
  const float* v1 = (const float*)d_in[8];
  const float* W2 = (const float*)d_in[9];
  const float* b2 = (const float*)d_in[10];
  const float* g2 = (const float*)d_in[11];
  const float* be2 = (const float*)d_in[12];
  const float* m2 = (const float*)d_in[13];
  const float* v2 = (const float*)d_in[14];
  const float* W3 = (const float*)d_in[15];
  const float* b3 = (const float*)d_in[16];
  float* out = (float*)d_out;

  char* wsb = (char*)d_ws;
  int* histM = (int*)wsb;                      wsb += (size_t)NSEG * NBUKP * 4;
  int* segbase = (int*)wsb;                    wsb += (size_t)NSEG * NBUKP * 4;
  int* btot = (int*)wsb;                       wsb += NBUKP * 4;
  uint4* nrange = (uint4*)wsb;                 wsb += (size_t)NN * 16;
  float* sc1 = (float*)wsb;                    wsb += FD * 4;
  float* sh1 = (float*)wsb;                    wsb += FD * 4;
  float* sc2 = (float*)wsb;                    wsb += FD * 4;
  float* sh2 = (float*)wsb;                    wsb += FD * 4;
  unsigned short* w1hi = (unsigned short*)wsb; wsb += FD * FD * 2;
  unsigned short* w1lo = (unsigned short*)wsb; wsb += FD * FD * 2;
  unsigned short* w2hi = (unsigned short*)wsb; wsb += FD * FD * 2;
  unsigned short* w2lo = (unsigned short*)wsb; wsb += FD * FD * 2;
  int* csr_src = (int*)wsb;                    wsb += (size_t)NBUK * BCAP * 4;
  unsigned int* buck = (unsigned int*)wsb;     wsb += (size_t)NBUK * BCAP * 4;
  float* AGG = (float*)wsb;                    wsb += (size_t)NN * FD * 4;
  unsigned short* Hbs = (unsigned short*)wsb;  wsb += (size_t)NN * FD * 2;
  float* H3s = (float*)wsb;                    wsb += (size_t)NN * CO * 4;

  k_hist_prep<<<NSEG + 129, 256, 0, stream>>>(dst, histM, W1, W2,
                                              w1hi, w1lo, w2hi, w2lo,
                                              b1, g1, be1, m1, v1,
                                              b2, g2, be2, m2, v2,
                                              sc1, sh1, sc2, sh2);
  k_colscan<<<NBUK, 256, 0, stream>>>(histM, segbase, btot);
  k_scatter2<<<NSEG, 256, 0, stream>>>(src, dst, segbase, buck);
  k_finalize<<<NBUK, 256, 0, stream>>>(btot, buck, nrange, csr_src);

  int gemm_blocks = (NN + 63) / 64;
  int gat_blocks = (NN + 3) / 4;

  // layer 1
  k_gemm128_mfma<<<gemm_blocks, 256, 0, stream>>>(x, w1hi, w1lo, nrange, Hbs, NN);
  k_gather128<<<gat_blocks, 256, 0, stream>>>(nrange, csr_src, Hbs, sc1, sh1, AGG);
  // layer 2 (+ fused output GEMM)
  k_gemm128_mfma<<<gemm_blocks, 256, 0, stream>>>(AGG, w2hi, w2lo, nrange, Hbs, NN);
  k_gather128_out<<<gat_blocks, 256, 0, stream>>>(nrange, csr_src, Hbs, sc2, sh2, W3, H3s);
  // layer 3 aggregation
  k_gather10<<<(NN + 15) / 16, 256, 0, stream>>>(nrange, csr_src, H3s, b3, out);
}

// Round 14
// 310.676 us; speedup vs baseline: 1.4457x; 1.0103x over previous
//
#include <hip/hip_runtime.h>

#define NN 100000
#define NE 1600000
#define FD 128
#define CO 10
#define BN_EPS 1e-5f
#define NBUK 782                               // buckets of 128 nodes
#define NBUKP 784
#define BCAP 3072
#define SEGE 8192
#define NSEG 196                               // ceil(NE/SEGE)
#define H3P 16                                 // padded H3s stride (64 B lines)

typedef __attribute__((ext_vector_type(8))) short short8;
typedef __attribute__((ext_vector_type(4))) float f32x4;

__device__ __forceinline__ unsigned short f2bf(float f) {
  unsigned int u = __builtin_bit_cast(unsigned int, f);
  u = (u + 0x7FFFu + ((u >> 16) & 1u)) >> 16;
  return (unsigned short)u;
}
__device__ __forceinline__ float bf2f(unsigned short h) {
  unsigned int u = ((unsigned int)h) << 16;
  return __builtin_bit_cast(float, u);
}
__device__ __forceinline__ float blo(unsigned int u) {
  return __builtin_bit_cast(float, u << 16);
}
__device__ __forceinline__ float bhi(unsigned int u) {
  return __builtin_bit_cast(float, u & 0xFFFF0000u);
}
__device__ __forceinline__ unsigned int cvt_pk_bf16(float a, float b) {
  unsigned int r;
  asm("v_cvt_pk_bf16_f32 %0, %1, %2" : "=v"(r) : "v"(a), "v"(b));
  return r;
}

// ---------------- fused: per-segment histogram + W-convert + BN constants ----
// blocks 0..NSEG-1: hist; NSEG..NSEG+127: W1/W2 bf16 hi/lo; NSEG+128: BN.
__global__ __launch_bounds__(256) void k_hist_prep(
    const int* __restrict__ dst, int* __restrict__ histM,
    const float* __restrict__ W1, const float* __restrict__ W2,
    unsigned short* __restrict__ w1hi, unsigned short* __restrict__ w1lo,
    unsigned short* __restrict__ w2hi, unsigned short* __restrict__ w2lo,
    const float* __restrict__ b1, const float* __restrict__ g1,
    const float* __restrict__ be1, const float* __restrict__ m1,
    const float* __restrict__ v1,
    const float* __restrict__ b2, const float* __restrict__ g2,
    const float* __restrict__ be2, const float* __restrict__ m2,
    const float* __restrict__ v2,
    float* __restrict__ sc1, float* __restrict__ sh1,
    float* __restrict__ sc2, float* __restrict__ sh2) {
  __shared__ int hist[NBUK];
  int b = blockIdx.x, t = threadIdx.x;
  if (b < NSEG) {
    for (int i = t; i < NBUK; i += 256) hist[i] = 0;
    __syncthreads();
    int e0 = b * SEGE, e1 = min(e0 + SEGE, NE);
    for (int e = e0 + t; e < e1; e += 256) atomicAdd(&hist[dst[e] >> 7], 1);
    __syncthreads();
    for (int i = t; i < NBUK; i += 256) histM[b * NBUKP + i] = hist[i];
  } else if (b < NSEG + 128) {
    int bb = b - NSEG;
    const float* W = (bb < 64) ? W1 : W2;
    unsigned short* whi = (bb < 64) ? w1hi : w2hi;
    unsigned short* wlo = (bb < 64) ? w1lo : w2lo;
    int i = (bb & 63) * 256 + t;
    int k = i >> 7, n = i & 127;
    float w = W[i];
    unsigned short h = f2bf(w);
    unsigned short l = f2bf(w - bf2f(h));
    int idx = ((((k >> 5) * 8) + (n >> 4)) * 64 + ((k >> 3) & 3) * 16 + (n & 15)) * 8 + (k & 7);
    whi[idx] = h;
    wlo[idx] = l;
  } else {
    if (t < FD) {
      float s = g1[t] * rsqrtf(v1[t] + BN_EPS);
      sc1[t] = s;
      sh1[t] = (b1[t] - m1[t]) * s + be1[t];
    } else if (t < 2 * FD) {
      int f = t - FD;
      float s = g2[f] * rsqrtf(v2[f] + BN_EPS);
      sc2[f] = s;
      sh2[f] = (b2[f] - m2[f]) * s + be2[f];
    }
  }
}

// ---------------- per-bucket prefix over segments ----------------
__global__ __launch_bounds__(256) void k_colscan(const int* __restrict__ histM,
                                                 int* __restrict__ segbase,
                                                 int* __restrict__ btot) {
  __shared__ int lds[256];
  int b = blockIdx.x, t = threadIdx.x;
  int v = (t < NSEG) ? histM[t * NBUKP + b] : 0;
  lds[t] = v;
  __syncthreads();
  int mine = v;
  for (int off = 1; off < 256; off <<= 1) {
    int add = (t >= off) ? lds[t - off] : 0;
    __syncthreads();
    lds[t] += add;
    __syncthreads();
  }
  if (t < NSEG) segbase[t * NBUKP + b] = lds[t] - mine;
  if (t == 255) btot[b] = lds[255];
}

// ---------------- scatter into buckets, LDS cursors, packed u32 -------------
__global__ __launch_bounds__(256) void k_scatter2(const int* __restrict__ src,
                                                  const int* __restrict__ dst,
                                                  const int* __restrict__ segbase,
                                                  unsigned int* __restrict__ buck) {
  __shared__ int base[NBUK];
  int b = blockIdx.x, t = threadIdx.x;
  for (int i = t; i < NBUK; i += 256) base[i] = segbase[b * NBUKP + i];
  __syncthreads();
  int e0 = b * SEGE, e1 = min(e0 + SEGE, NE);
  for (int e = e0 + t; e < e1; e += 256) {
    int s = src[e], d = dst[e];
    int bk = d >> 7;
    int slot = atomicAdd(&base[bk], 1);
    buck[(size_t)bk * BCAP + slot] = ((unsigned int)(d & 127) << 17) | (unsigned int)s;
  }
}

// ---------------- finalize: count + local scan + nrange + place -------------
__global__ __launch_bounds__(256) void k_finalize(const int* __restrict__ btot,
                                                  const unsigned int* __restrict__ buck,
                                                  uint4* __restrict__ nrange,
                                                  int* __restrict__ csr_src) {
  __shared__ unsigned int ebuf[BCAP];  // 12 KB
  __shared__ int cnt[128];
  __shared__ int xoff[128];
  int b = blockIdx.x, t = threadIdx.x;
  int nb = btot[b];
  const unsigned int* bp = buck + (size_t)b * BCAP;
  for (int i = t; i < nb; i += 256) ebuf[i] = bp[i];
  if (t < 128) cnt[t] = 0;
  __syncthreads();
  for (int i = t; i < nb; i += 256) atomicAdd(&cnt[ebuf[i] >> 17], 1);
  __syncthreads();
  if (t < 128) xoff[t] = cnt[t];
  __syncthreads();
  for (int off = 1; off < 128; off <<= 1) {
    int add = 0;
    if (t < 128 && t >= off) add = xoff[t - off];
    __syncthreads();
    if (t < 128) xoff[t] += add;
    __syncthreads();
  }
  if (t < 128) {
    int node = b * 128 + t;
    int ex = xoff[t] - cnt[t];
    if (node < NN) {
      uint4 nr;
      nr.x = (unsigned)(b * BCAP + ex);
      nr.y = (unsigned)cnt[t];
      nr.z = __builtin_bit_cast(unsigned int, rsqrtf((float)cnt[t] + 1.0f));
      nr.w = 0;
      nrange[node] = nr;
    }
    xoff[t] = ex;
    cnt[t] = 0;
  }
  __syncthreads();
  int base = b * BCAP;
  for (int i = t; i < nb; i += 256) {
    unsigned int p = ebuf[i];
    int dl = (int)(p >> 17);
    int l = atomicAdd(&cnt[dl], 1);
    csr_src[base + xoff[dl] + l] = (int)(p & 0x1FFFFu);
  }
}

// ---------------- layer-1 MFMA GEMM (f32 A, bf16x3) -> pre-scaled bf16 rows --
__global__ __launch_bounds__(256) void k_gemm128_mfma(const float* __restrict__ X,
                                                      const unsigned short* __restrict__ whi,
                                                      const unsigned short* __restrict__ wlo,
                                                      const uint4* __restrict__ nrange,
                                                      unsigned short* __restrict__ Hbs,
                                                      int nrows) {
  int tid = threadIdx.x;
  int lane = tid & 63, wv = tid >> 6;
  int lg = lane >> 4, li = lane & 15;
  int wr0 = blockIdx.x * 64 + wv * 16;
  int row = wr0 + li;
  bool ok = row < nrows;

  short8 ahi[4], alo[4];
#pragma unroll
  for (int ks = 0; ks < 4; ++ks) {
    if (ok) {
      const float* xp = X + (unsigned)(row * FD + ks * 32 + lg * 8);
      float4 v0 = *(const float4*)xp;
      float4 v1 = *(const float4*)(xp + 4);
      float f[8] = {v0.x, v0.y, v0.z, v0.w, v1.x, v1.y, v1.z, v1.w};
      unsigned int hp[4], lp[4];
#pragma unroll
      for (int j = 0; j < 4; ++j) {
        float a = f[2 * j], c = f[2 * j + 1];
        hp[j] = cvt_pk_bf16(a, c);
        float ra = a - blo(hp[j]);
        float rc = c - bhi(hp[j]);
        lp[j] = cvt_pk_bf16(ra, rc);
      }
      uint4 hv = {hp[0], hp[1], hp[2], hp[3]};
      uint4 lv = {lp[0], lp[1], lp[2], lp[3]};
      ahi[ks] = __builtin_bit_cast(short8, hv);
      alo[ks] = __builtin_bit_cast(short8, lv);
    } else {
#pragma unroll
      for (int j = 0; j < 8; ++j) { ahi[ks][j] = 0; alo[ks][j] = 0; }
    }
  }

  int rb = wr0 + lg * 4;
  float dvr[4];
#pragma unroll
  for (int r = 0; r < 4; ++r)
    dvr[r] = (rb + r < nrows) ? __builtin_bit_cast(float, nrange[rb + r].z) : 0.f;

#pragma unroll
  for (int nt = 0; nt < 8; ++nt) {
    f32x4 acc = {0.f, 0.f, 0.f, 0.f};
#pragma unroll
    for (int ks = 0; ks < 4; ++ks) {
      unsigned int bidx = (unsigned)(((ks * 8 + nt) * 64 + lane) * 8);
      short8 bh = *(const short8*)&whi[bidx];
      short8 bl = *(const short8*)&wlo[bidx];
      acc = __builtin_amdgcn_mfma_f32_16x16x32_bf16(ahi[ks], bh, acc, 0, 0, 0);
      acc = __builtin_amdgcn_mfma_f32_16x16x32_bf16(alo[ks], bh, acc, 0, 0, 0);
      acc = __builtin_amdgcn_mfma_f32_16x16x32_bf16(ahi[ks], bl, acc, 0, 0, 0);
    }
    int col = nt * 16 + li;   // C/D: col=lane&15, row=(lane>>4)*4+reg [m89]
#pragma unroll
    for (int r = 0; r < 4; ++r) {
      if (rb + r < nrows)
        Hbs[(unsigned)((rb + r) * FD + col)] = f2bf(acc[r] * dvr[r]);
    }
  }
}

// ---------------- layer-2 MFMA GEMM (bf16 A: 2 MFMAs) -> pre-scaled bf16 ----
__global__ __launch_bounds__(256) void k_gemm128_bf16A(const unsigned short* __restrict__ Ab,
                                                       const unsigned short* __restrict__ whi,
                                                       const unsigned short* __restrict__ wlo,
                                                       const uint4* __restrict__ nrange,
                                                       unsigned short* __restrict__ Hbs,
                                                       int nrows) {
  int tid = threadIdx.x;
  int lane = tid & 63, wv = tid >> 6;
  int lg = lane >> 4, li = lane & 15;
  int wr0 = blockIdx.x * 64 + wv * 16;
  int row = wr0 + li;
  bool ok = row < nrows;

  short8 ahi[4];
#pragma unroll
  for (int ks = 0; ks < 4; ++ks) {
    if (ok) {
      ahi[ks] = *(const short8*)(Ab + (unsigned)(row * FD + ks * 32 + lg * 8));
    } else {
#pragma unroll
      for (int j = 0; j < 8; ++j) ahi[ks][j] = 0;
    }
  }

  int rb = wr0 + lg * 4;
  float dvr[4];
#pragma unroll
  for (int r = 0; r < 4; ++r)
    dvr[r] = (rb + r < nrows) ? __builtin_bit_cast(float, nrange[rb + r].z) : 0.f;

#pragma unroll
  for (int nt = 0; nt < 8; ++nt) {
    f32x4 acc = {0.f, 0.f, 0.f, 0.f};
#pragma unroll
    for (int ks = 0; ks < 4; ++ks) {
      unsigned int bidx = (unsigned)(((ks * 8 + nt) * 64 + lane) * 8);
      short8 bh = *(const short8*)&whi[bidx];
      short8 bl = *(const short8*)&wlo[bidx];
      acc = __builtin_amdgcn_mfma_f32_16x16x32_bf16(ahi[ks], bh, acc, 0, 0, 0);
      acc = __builtin_amdgcn_mfma_f32_16x16x32_bf16(ahi[ks], bl, acc, 0, 0, 0);
    }
    int col = nt * 16 + li;
#pragma unroll
    for (int r = 0; r < 4; ++r) {
      if (rb + r < nrows)
        Hbs[(unsigned)((rb + r) * FD + col)] = f2bf(acc[r] * dvr[r]);
    }
  }
}

// ---------------- layer-1 gather: bf16 rows -> BN+ReLU -> bf16 AGGb ---------
__global__ __launch_bounds__(256) void k_gather128(const uint4* __restrict__ nrange,
                                                   const int* __restrict__ csr_src,
                                                   const unsigned short* __restrict__ Hbs,
                                                   const float* __restrict__ sc,
                                                   const float* __restrict__ sh,
                                                   unsigned int* __restrict__ AGGb) {
  int node = blockIdx.x * 4 + (threadIdx.x >> 6);   // NN % 4 == 0
  node = __builtin_amdgcn_readfirstlane(node);
  int lane = threadIdx.x & 63;
  const unsigned int* Hc = (const unsigned int*)Hbs;
  uint4 nr = nrange[node];
  int beg = (int)nr.x, end = (int)(nr.x + nr.y);
  float dv = __builtin_bit_cast(float, nr.z);
  float px0, px1 = 0.f, px2 = 0.f, px3 = 0.f;
  float py0, py1 = 0.f, py2 = 0.f, py3 = 0.f;
  {
    unsigned int us = Hc[(unsigned)(node * 64) + lane];
    px0 = blo(us); py0 = bhi(us);
  }
  int e = beg;
  for (; e + 3 < end; e += 4) {
    unsigned int u0 = Hc[((unsigned)csr_src[e + 0] << 6) + lane];
    unsigned int u1 = Hc[((unsigned)csr_src[e + 1] << 6) + lane];
    unsigned int u2 = Hc[((unsigned)csr_src[e + 2] << 6) + lane];
    unsigned int u3 = Hc[((unsigned)csr_src[e + 3] << 6) + lane];
    px0 += blo(u0); py0 += bhi(u0);
    px1 += blo(u1); py1 += bhi(u1);
    px2 += blo(u2); py2 += bhi(u2);
    px3 += blo(u3); py3 += bhi(u3);
  }
  for (; e < end; ++e) {
    unsigned int u0 = Hc[((unsigned)csr_src[e] << 6) + lane];
    px0 += blo(u0); py0 += bhi(u0);
  }
  float accx = ((px0 + px1) + (px2 + px3)) * dv;
  float accy = ((py0 + py1) + (py2 + py3)) * dv;
  float scx = sc[lane * 2], scy = sc[lane * 2 + 1];
  float shx = sh[lane * 2], shy = sh[lane * 2 + 1];
  accx = fmaxf(fmaf(accx, scx, shx), 0.f);
  accy = fmaxf(fmaf(accy, scy, shy), 0.f);
  AGGb[(unsigned)(node * 64) + lane] = cvt_pk_bf16(accx, accy);
}

// ---------------- layer-2 gather + BN + fused W3 GEMM -> pre-scaled H3s -----
__global__ __launch_bounds__(256) void k_gather128_out(const uint4* __restrict__ nrange,
                                                       const int* __restrict__ csr_src,
                                                       const unsigned short* __restrict__ Hbs,
                                                       const float* __restrict__ sc,
                                                       const float* __restrict__ sh,
                                                       const float* __restrict__ W3,
                                                       float* __restrict__ H3s) {
  int node = blockIdx.x * 4 + (threadIdx.x >> 6);
  node = __builtin_amdgcn_readfirstlane(node);
  int lane = threadIdx.x & 63;
  float w3r[20];
  {
    const float* wp = W3 + lane * 2 * CO;
#pragma unroll
    for (int j = 0; j < 20; ++j) w3r[j] = wp[j];
  }
  const unsigned int* Hc = (const unsigned int*)Hbs;
  uint4 nr = nrange[node];
  int beg = (int)nr.x, end = (int)(nr.x + nr.y);
  float dv = __builtin_bit_cast(float, nr.z);
  float px0, px1 = 0.f, px2 = 0.f, px3 = 0.f;
  float py0, py1 = 0.f, py2 = 0.f, py3 = 0.f;
  {
    unsigned int us = Hc[(unsigned)(node * 64) + lane];
    px0 = blo(us); py0 = bhi(us);
  }
  int e = beg;
  for (; e + 3 < end; e += 4) {
    unsigned int u0 = Hc[((unsigned)csr_src[e + 0] << 6) + lane];
    unsigned int u1 = Hc[((unsigned)csr_src[e + 1] << 6) + lane];
    unsigned int u2 = Hc[((unsigned)csr_src[e + 2] << 6) + lane];
    unsigned int u3 = Hc[((unsigned)csr_src[e + 3] << 6) + lane];
    px0 += blo(u0); py0 += bhi(u0);
    px1 += blo(u1); py1 += bhi(u1);
    px2 += blo(u2); py2 += bhi(u2);
    px3 += blo(u3); py3 += bhi(u3);
  }
  for (; e < end; ++e) {
    unsigned int u0 = Hc[((unsigned)csr_src[e] << 6) + lane];
    px0 += blo(u0); py0 += bhi(u0);
  }
  float accx = ((px0 + px1) + (px2 + px3)) * dv;
  float accy = ((py0 + py1) + (py2 + py3)) * dv;
  float scx = sc[lane * 2], scy = sc[lane * 2 + 1];
  float shx = sh[lane * 2], shy = sh[lane * 2 + 1];
  accx = fmaxf(fmaf(accx, scx, shx), 0.f);
  accy = fmaxf(fmaf(accy, scy, shy), 0.f);
  float p[10];
#pragma unroll
  for (int c = 0; c < CO; ++c) p[c] = fmaf(accx, w3r[c], accy * w3r[10 + c]);
#pragma unroll
  for (int off = 32; off >= 1; off >>= 1) {
#pragma unroll
    for (int c = 0; c < CO; ++c) p[c] += __shfl_xor(p[c], off);
  }
#pragma unroll
  for (int c = 0; c < CO; ++c)
    if (lane == c) H3s[(unsigned)(node * H3P + c)] = p[c] * dv;
}

// ---------------- gather 10 feat over pre-scaled H3s (stride 16) ------------
__global__ __launch_bounds__(256) void k_gather10(const uint4* __restrict__ nrange,
                                                  const int* __restrict__ csr_src,
                                                  const float* __restrict__ H3s,
                                                  const float* __restrict__ b3,
                                                  float* __restrict__ out) {
  int node = blockIdx.x * 16 + (threadIdx.x >> 4);
  if (node >= NN) return;
  int c = threadIdx.x & 15;
  uint4 nr = nrange[node];
  int beg = (int)nr.x, end = (int)(nr.x + nr.y);
  float dv = __builtin_bit_cast(float, nr.z);
  float acc = 0.f;
  if (c < CO) acc = H3s[(unsigned)(node * H3P + c)];
  for (int e = beg; e < end; ++e) {
    int s = csr_src[e];
    if (c < CO) acc += H3s[(unsigned)(s * H3P + c)];
  }
  if (c < CO) out[(unsigned)(node * CO + c)] = fmaf(acc, dv, b3[c]);
}

// ---------------- launch ----------------
extern "C" void kernel_launch(void* const* d_in, const int* in_sizes, int n_in,
                              void* d_out, int out_size, void* d_ws, size_t ws_size,
                              hipStream_t stream) {
  const float* x = (const float*)d_in[0];
  const int* src = (const int*)d_in[1];
  const int* dst = (const int*)d_in[2];
  const float* W1 = (const float*)d_in[3];
  const float* b1 = (const float*)d_in[4];
  const float* g1 = (const float*)d_in[5];
  const float* be1 = (const float*)d_in[6];
  const float* m1 = (const float*)d_in[7];
  const float* v1 = (const float*)d_in[8];
  const float* W2 = (const float*)d_in[9];
  const float* b2 = (const float*)d_in[10];
  const float* g2 = (const float*)d_in[11];
  const float* be2 = (const float*)d_in[12];
  const float* m2 = (const float*)d_in[13];
  const float* v2 = (const float*)d_in[14];
  const float* W3 = (const float*)d_in[15];
  const float* b3 = (const float*)d_in[16];
  float* out = (float*)d_out;

  char* wsb = (char*)d_ws;
  int* histM = (int*)wsb;                      wsb += (size_t)NSEG * NBUKP * 4;
  int* segbase = (int*)wsb;                    wsb += (size_t)NSEG * NBUKP * 4;
  int* btot = (int*)wsb;                       wsb += NBUKP * 4;
  uint4* nrange = (uint4*)wsb;                 wsb += (size_t)NN * 16;
  float* sc1 = (float*)wsb;                    wsb += FD * 4;
  float* sh1 = (float*)wsb;                    wsb += FD * 4;
  float* sc2 = (float*)wsb;                    wsb += FD * 4;
  float* sh2 = (float*)wsb;                    wsb += FD * 4;
  unsigned short* w1hi = (unsigned short*)wsb; wsb += FD * FD * 2;
  unsigned short* w1lo = (unsigned short*)wsb; wsb += FD * FD * 2;
  unsigned short* w2hi = (unsigned short*)wsb; wsb += FD * FD * 2;
  unsigned short* w2lo = (unsigned short*)wsb; wsb += FD * FD * 2;
  int* csr_src = (int*)wsb;                    wsb += (size_t)NBUK * BCAP * 4;
  unsigned int* buck = (unsigned int*)wsb;     wsb += (size_t)NBUK * BCAP * 4;
  unsigned int* AGGb = (unsigned int*)wsb;     wsb += (size_t)NN * FD * 2;  // bf16 [N][128]
  unsigned short* Hbs = (unsigned short*)wsb;  wsb += (size_t)NN * FD * 2;
  float* H3s = (float*)wsb;                    wsb += (size_t)NN * H3P * 4;

  k_hist_prep<<<NSEG + 129, 256, 0, stream>>>(dst, histM, W1, W2,
                                              w1hi, w1lo, w2hi, w2lo,
                                              b1, g1, be1, m1, v1,
                                              b2, g2, be2, m2, v2,
                                              sc1, sh1, sc2, sh2);
  k_colscan<<<NBUK, 256, 0, stream>>>(histM, segbase, btot);
  k_scatter2<<<NSEG, 256, 0, stream>>>(src, dst, segbase, buck);
  k_finalize<<<NBUK, 256, 0, stream>>>(btot, buck, nrange, csr_src);

  int gemm_blocks = (NN + 63) / 64;
  int gat_blocks = (NN + 3) / 4;

  // layer 1
  k_gemm128_mfma<<<gemm_blocks, 256, 0, stream>>>(x, w1hi, w1lo, nrange, Hbs, NN);
  k_gather128<<<gat_blocks, 256, 0, stream>>>(nrange, csr_src, Hbs, sc1, sh1, AGGb);
  // layer 2 (bf16 A) + fused output GEMM
  k_gemm128_bf16A<<<gemm_blocks, 256, 0, stream>>>((const unsigned short*)AGGb,
                                                   w2hi, w2lo, nrange, Hbs, NN);
  k_gather128_out<<<gat_blocks, 256, 0, stream>>>(nrange, csr_src, Hbs, sc2, sh2, W3, H3s);
  // layer 3 aggregation
  k_gather10<<<(NN + 15) / 16, 256, 0, stream>>>(nrange, csr_src, H3s, b3, out);
}